// Round 9
// baseline (259.840 us; speedup 1.0000x reference)
//
#include <hip/hip_runtime.h>
#include <hip/hip_bf16.h>

typedef unsigned short ushort;
typedef unsigned int uint;
typedef __bf16 bf16x8 __attribute__((ext_vector_type(8)));
typedef float f32x4 __attribute__((ext_vector_type(4)));
typedef ushort ushort8 __attribute__((ext_vector_type(8)));

#define LOG2E 1.4426950408889634f
#define MFMA16(a,b,c) __builtin_amdgcn_mfma_f32_16x16x32_bf16((a),(b),(c),0,0,0)
#define GLL4(src, dst) __builtin_amdgcn_global_load_lds( \
    (const __attribute__((address_space(1))) void*)(src), \
    (__attribute__((address_space(3))) void*)(dst), 4, 0, 0)

static __device__ __forceinline__ uint packbf(float lo, float hi) {
  union { __bf16 h[2]; uint u; } x;
  x.h[0] = (__bf16)lo; x.h[1] = (__bf16)hi;
  return x.u;
}
static __device__ __forceinline__ int cellof(float x) {
  int c = (int)(x * 0.015625f);           // /64
  return c < 0 ? 0 : (c > 9 ? 9 : c);
}

// ---------------------------------------------------------------------------
// cast 4 weight matrices f32->bf16; block (0,0) also zeroes counters
// ---------------------------------------------------------------------------
__global__ __launch_bounds__(256) void cast_weights(
    const float* __restrict__ W0, const float* __restrict__ W1,
    const float* __restrict__ W2, const float* __restrict__ W3,
    __bf16* __restrict__ out,
    int* __restrict__ hist, int* __restrict__ curs, float* __restrict__ meanN)
{
  if (blockIdx.x == 0 && blockIdx.y == 0) {
    int t = threadIdx.x;
    for (int i = t; i < 1024; i += 256) { hist[i] = 0; curs[i] = 0; meanN[i] = 0.f; }
  }
  const int which = blockIdx.y;
  const float* src = which == 0 ? W0 : which == 1 ? W1 : which == 2 ? W2 : W3;
  const int i = (blockIdx.x * 256 + threadIdx.x) * 4;
  f32x4 v = *(const f32x4*)(src + i);
  union { __bf16 h[4]; uint u[2]; } x;
  #pragma unroll
  for (int j = 0; j < 4; j++) x.h[j] = (__bf16)v[j];
  *(uint*)(out + (size_t)which * 65536 + i) = x.u[0];
  *(uint*)(out + (size_t)which * 65536 + i + 2) = x.u[1];
}

// ---------------------------------------------------------------------------
// histogram points into 10x10 cells. type0 = queries(kpred), type1 = keys(kact)
// ---------------------------------------------------------------------------
__global__ __launch_bounds__(256) void hist_kernel(
    const float* __restrict__ kpred, const float* __restrict__ kact,
    int* __restrict__ hist, int* __restrict__ cellpt)
{
  int p = blockIdx.x * 256 + threadIdx.x;     // 0..32767
  int type = p >> 14, idx = p & 16383;
  const float2 c = ((const float2*)(type == 0 ? kpred : kact))[idx];
  int cell = cellof(c.x) * 10 + cellof(c.y);
  int b = idx >> 12;
  atomicAdd(&hist[(type * 4 + b) * 128 + cell], 1);
  cellpt[type * 16384 + idx] = cell;
}

// ---------------------------------------------------------------------------
// exclusive scan of 8 segments x 100 cells -> start[seg][0..100], cursor copy
// ---------------------------------------------------------------------------
__global__ __launch_bounds__(256) void scan_kernel(
    const int* __restrict__ hist, int* __restrict__ strt, int* __restrict__ curs)
{
  __shared__ int sh[1024];
  int t = threadIdx.x;
  for (int i = t; i < 1024; i += 256) sh[i] = hist[i];
  __syncthreads();
  if (t < 8) {
    int run = 0;
    for (int c = 0; c < 100; c++) {
      strt[t * 128 + c] = run;
      curs[t * 128 + c] = run;
      run += sh[t * 128 + c];
    }
    strt[t * 128 + 100] = run;   // sentinel (=4096)
  }
}

// ---------------------------------------------------------------------------
// scatter: sorted index arrays, inverse perms, sorted coords (both types)
// ---------------------------------------------------------------------------
__global__ __launch_bounds__(256) void scatter_kernel(
    const float* __restrict__ kpred, const float* __restrict__ kact,
    const int* __restrict__ cellpt, int* __restrict__ curs,
    int* __restrict__ sq, int* __restrict__ invq, float* __restrict__ kpS,
    int* __restrict__ sk, int* __restrict__ invk, float* __restrict__ kaS)
{
  int p = blockIdx.x * 256 + threadIdx.x;
  int type = p >> 14, idx = p & 16383;
  int b = idx >> 12, n = idx & 4095;
  int cell = cellpt[type * 16384 + idx];
  int pos = atomicAdd(&curs[(type * 4 + b) * 128 + cell], 1);
  if (type == 0) {
    sq[b * 4096 + pos] = n;
    invq[b * 4096 + n] = pos;
    ((float2*)kpS)[b * 4096 + pos] = ((const float2*)kpred)[idx];
  } else {
    sk[b * 4096 + pos] = n;
    invk[b * 4096 + n] = pos;
    ((float2*)kaS)[b * 4096 + pos] = ((const float2*)kact)[idx];
  }
}

// ---------------------------------------------------------------------------
__global__ __launch_bounds__(256) void meansum_kernel(
    const float* __restrict__ nodes_t1, float* __restrict__ meanN)
{
  int b = blockIdx.y, chunk = blockIdx.x, c = threadIdx.x;
  const float* base = nodes_t1 + ((size_t)b * 4096 + chunk * 256) * 256 + c;
  float s = 0.f;
  for (int r = 0; r < 256; r++) s += base[(size_t)r * 256];
  atomicAdd(&meanN[b * 256 + c], s);
}

__global__ __launch_bounds__(256) void vmean_kernel(
    const float* __restrict__ meanN, const float* __restrict__ Wv,
    const float* __restrict__ bv, float* __restrict__ Vmean)
{
  __shared__ float mn[256];
  int b = blockIdx.x, d = threadIdx.x;
  mn[d] = meanN[b * 256 + d] * (1.0f / 4096.0f);
  __syncthreads();
  float s = bv[d];
  const float* w = Wv + (size_t)d * 256;
  for (int c = 0; c < 256; c++) s += mn[c] * w[c];
  Vmean[b * 256 + d] = s;
}

// ---------------------------------------------------------------------------
// fused Q/K/V projection GEMM (blockIdx.z = 0/1/2), f32 A cast in-reg.
// ALL outputs row-scattered into sorted order (coalesced 512B rows).
// ---------------------------------------------------------------------------
__global__ __launch_bounds__(256) void gemm_qkv(
    const float* __restrict__ nodes_t, const float* __restrict__ nodes_t1,
    const ushort* __restrict__ W4,
    const float* __restrict__ bq, const float* __restrict__ bk,
    const float* __restrict__ bv,
    __bf16* __restrict__ outQ, __bf16* __restrict__ outK,
    __bf16* __restrict__ outVs,
    const int* __restrict__ invq, const int* __restrict__ invk)
{
  const int z = blockIdx.z;
  const float* A = z == 0 ? nodes_t : nodes_t1;
  const ushort* W = W4 + z * 65536;
  const float* bias = z == 0 ? bq : (z == 1 ? bk : bv);
  const int* inv = z == 0 ? invq : invk;

  const int wid = threadIdx.x >> 6;
  const int lane = threadIdx.x & 63;
  const int q = lane & 15, g = lane >> 4;
  const int nb = blockIdx.x * 64 + (wid >> 1) * 32;
  const int db = blockIdx.y * 128 + (wid & 1) * 64;

  f32x4 acc[2][4];
  #pragma unroll
  for (int a = 0; a < 2; a++)
    #pragma unroll
    for (int b = 0; b < 4; b++) acc[a][b] = f32x4{0.f,0.f,0.f,0.f};

  const ushort* W0 = W + (size_t)(db + q) * 256 + g * 8;

  #pragma unroll
  for (int c0 = 0; c0 < 256; c0 += 32) {
    bf16x8 a0, a1;
    const float* Ar0 = A + (size_t)(nb + q) * 256 + g * 8 + c0;
    const float* Ar1 = A + (size_t)(nb + 16 + q) * 256 + g * 8 + c0;
    f32x4 u0 = *(const f32x4*)Ar0, u1 = *(const f32x4*)(Ar0 + 4);
    f32x4 w0 = *(const f32x4*)Ar1, w1 = *(const f32x4*)(Ar1 + 4);
    #pragma unroll
    for (int j = 0; j < 4; j++) {
      a0[j] = (__bf16)u0[j]; a0[4 + j] = (__bf16)u1[j];
      a1[j] = (__bf16)w0[j]; a1[4 + j] = (__bf16)w1[j];
    }
    #pragma unroll
    for (int df = 0; df < 4; df++) {
      bf16x8 w = *(const bf16x8*)(W0 + df * 16 * 256 + c0);
      acc[0][df] = MFMA16(a0, w, acc[0][df]);
      acc[1][df] = MFMA16(a1, w, acc[1][df]);
    }
  }
  __bf16* o = z == 0 ? outQ : (z == 1 ? outK : outVs);
  #pragma unroll
  for (int df = 0; df < 4; df++) {
    float bval = bias[db + df * 16 + q];
    #pragma unroll
    for (int nf = 0; nf < 2; nf++)
      #pragma unroll
      for (int r = 0; r < 4; r++) {
        int row = nb + nf * 16 + g * 4 + r;
        int d = db + df * 16 + q;
        float val = acc[nf][df][r] + bval;
        int pos = inv[row];
        o[((size_t)(row & ~4095) + pos) * 256 + d] = (__bf16)val;
      }
  }
}

// ---------------------------------------------------------------------------
// transpose V_s [4][4096][256] -> VT [4][256][4096], LDS 64x64 tiles
// ---------------------------------------------------------------------------
__global__ __launch_bounds__(256) void transpose_v(
    const ushort* __restrict__ Vs, ushort* __restrict__ VT)
{
  __shared__ ushort tile[64][76];
  const int b = blockIdx.z, rt = blockIdx.x, dt = blockIdx.y;
  const int tid = threadIdx.x;
  const ushort* src = Vs + ((size_t)b * 4096 + rt * 64) * 256 + dt * 64;
  #pragma unroll
  for (int i = 0; i < 2; i++) {
    int c = tid + i * 256;
    int r = c >> 3, dc = (c & 7) * 8;
    ushort8 v = *(const ushort8*)(src + (size_t)r * 256 + dc);
    #pragma unroll
    for (int j = 0; j < 8; j++) tile[r][dc + j] = v[j];
  }
  __syncthreads();
  ushort* dst = VT + ((size_t)b * 256 + dt * 64) * 4096 + rt * 64;
  #pragma unroll
  for (int i = 0; i < 2; i++) {
    int c = tid + i * 256;
    int d = c >> 3, rc = (c & 7) * 8;
    ushort8 v;
    #pragma unroll
    for (int j = 0; j < 8; j++) v[j] = tile[rc + j][d];
    *(ushort8*)(dst + (size_t)d * 4096 + rc) = v;
  }
}

// ---------------------------------------------------------------------------
// merged GEMM: bf16 A (wsM) -> f32 out
// ---------------------------------------------------------------------------
__global__ __launch_bounds__(256) void gemm_merged(
    const ushort* __restrict__ A, const ushort* __restrict__ W,
    const float* __restrict__ bias, float* __restrict__ out)
{
  const int wid = threadIdx.x >> 6;
  const int lane = threadIdx.x & 63;
  const int q = lane & 15, g = lane >> 4;
  const int nb = blockIdx.x * 64 + (wid >> 1) * 32;
  const int db = blockIdx.y * 128 + (wid & 1) * 64;

  f32x4 acc[2][4];
  #pragma unroll
  for (int a = 0; a < 2; a++)
    #pragma unroll
    for (int b = 0; b < 4; b++) acc[a][b] = f32x4{0.f,0.f,0.f,0.f};

  const ushort* W0 = W + (size_t)(db + q) * 256 + g * 8;
  const ushort* Ar0 = A + (size_t)(nb + q) * 256 + g * 8;
  const ushort* Ar1 = A + (size_t)(nb + 16 + q) * 256 + g * 8;

  #pragma unroll
  for (int c0 = 0; c0 < 256; c0 += 32) {
    bf16x8 a0 = *(const bf16x8*)(Ar0 + c0);
    bf16x8 a1 = *(const bf16x8*)(Ar1 + c0);
    #pragma unroll
    for (int df = 0; df < 4; df++) {
      bf16x8 w = *(const bf16x8*)(W0 + df * 16 * 256 + c0);
      acc[0][df] = MFMA16(a0, w, acc[0][df]);
      acc[1][df] = MFMA16(a1, w, acc[1][df]);
    }
  }
  #pragma unroll
  for (int df = 0; df < 4; df++) {
    float bval = bias[db + df * 16 + q];
    #pragma unroll
    for (int nf = 0; nf < 2; nf++)
      #pragma unroll
      for (int r = 0; r < 4; r++) {
        int row = nb + nf * 16 + g * 4 + r;
        out[(size_t)row * 256 + db + df * 16 + q] = acc[nf][df][r] + bval;
      }
  }
}

// ---------------------------------------------------------------------------
// Cooperative cell-block sparse flash attention, reg-staged coalesced tiles.
// Block = (batch, cell); 4 waves = up to 4 query-tiles sharing the 3x3 ring.
// Per key-tile: 8 coalesced global b128 loads/wave -> regs (issued early,
// T14), compute from LDS, then ds_write next tile (K XOR-swizzled unit idx).
// ---------------------------------------------------------------------------
__global__ __launch_bounds__(256, 2) void attn_kernel(
    const ushort* __restrict__ Q,    // sorted Q_s [B*4096][256]
    const ushort* __restrict__ K,    // sorted K_s [B*4096][256]
    const ushort* __restrict__ VT,   // sorted VT_s [4][256][4096]
    const float* __restrict__ kpS,   // sorted pred coords
    const int* __restrict__ iter_idx,
    const int* __restrict__ sq,      // sorted->original query index
    const int* __restrict__ strt,    // [8][128], key segs at +4*128
    const float* __restrict__ kaS,   // sorted key coords
    const float* __restrict__ Vmean,
    __bf16* __restrict__ matched,
    float* __restrict__ out_flow, float* __restrict__ out_conf)
{
  __shared__ __align__(16) ushort Kl[2][8192];   // [buf] unit-major, col^=(u&7)
  __shared__ __align__(16) ushort Vl[2][8192];   // [buf] plane-major [4][256]
  __shared__ __align__(16) float2 Cl[2][32];
  __shared__ int tl_t[132], tl_ks[132], tl_ke[132];
  __shared__ int ntile_s;

  const int tid = threadIdx.x;
  const int wid = tid >> 6, lane = tid & 63;
  const int q = lane & 15, g = lane >> 4;
  const int batch = blockIdx.x & 3;
  const int cell = blockIdx.x >> 2;

  const int qstart = strt[batch * 128 + cell];
  const int nq = strt[batch * 128 + cell + 1] - qstart;
  if (nq == 0) return;

  const int cu = cell / 10, cv = cell % 10;
  const int c0 = cv > 0 ? cv - 1 : 0, c1 = cv < 9 ? cv + 1 : 9;
  const int* kst = strt + (4 + batch) * 128;

  if (tid == 0) {
    int n = 0;
    int lo = cu > 0 ? cu - 1 : 0, hi = cu < 9 ? cu + 1 : 9;
    for (int cc = lo; cc <= hi; cc++) {
      int ks = kst[cc * 10 + c0];
      int ke = kst[cc * 10 + c1 + 1];
      for (int t = ks & ~31; t < ke; t += 32) {
        tl_t[n] = t; tl_ks[n] = ks; tl_ke[n] = ke; n++;
      }
    }
    ntile_s = n;
  }
  __syncthreads();
  const int ntile = ntile_s;

  const int idx = *iter_idx;
  const float win = (idx == 0) ? 64.0f : fmaxf(4.0f, ldexpf(32.0f, 1 - idx));

  const ushort* Kbase = K + (size_t)batch * 4096 * 256;
  const ushort* VTb = VT + (size_t)batch * 1048576;
  const float* kasf = kaS + (size_t)batch * 8192;
  const float* Vm = Vmean + batch * 256;

  const int npass = (nq + 63) >> 6;

  // staged-tile registers (coalesced loads: full 64B lines only)
  uint4 kreg[4], vreg[4];

  auto STAGE_LOAD = [&](int ti, int buf) {
    const int t = tl_t[ti];
    #pragma unroll
    for (int j = 0; j < 4; j++) {   // K: 2 full rows (512B) per load
      int r = wid * 8 + j * 2 + (lane >> 5);
      kreg[j] = *(const uint4*)(Kbase + (size_t)(t + r) * 256 + (lane & 31) * 8);
    }
    #pragma unroll
    for (int j = 0; j < 4; j++) {   // V: 16 d-rows x 64B per load
      int d = wid * 64 + j * 16 + (lane >> 2);
      vreg[j] = *(const uint4*)(VTb + (size_t)d * 4096 + t + (lane & 3) * 8);
    }
    if (wid == 0) GLL4(kasf + t * 2 + lane, &Cl[buf][0]);
  };

  auto STAGE_WRITE = [&](int buf) {
    #pragma unroll
    for (int j = 0; j < 4; j++) {   // K unit-major, column r XOR-swizzled
      int r = wid * 8 + j * 2 + (lane >> 5);
      int u = lane & 31;
      *(uint4*)&Kl[buf][(u * 32 + (r ^ (u & 7))) * 8] = kreg[j];
    }
    #pragma unroll
    for (int j = 0; j < 4; j++) {   // V plane-major (balanced as-is)
      int d = wid * 64 + j * 16 + (lane >> 2);
      *(uint4*)&Vl[buf][((lane & 3) * 256 + d) * 8] = vreg[j];
    }
  };

  // per-pass / per-wave query state
  int cnt = 0, qi = 0;
  bool active = false;
  float pu = 0.f, pv = 0.f;
  bf16x8 qf[8];
  f32x4 O[16];
  float m_run = -1e9f, l_run = 0.f, u_run = 0.f, v_run = 0.f;

  auto PASS_INIT = [&](int pp) {
    int tbase = pp * 64 + wid * 16;
    active = tbase < nq;
    cnt = active ? min(16, nq - tbase) : 0;
    if (active) {
      int qq = q < cnt ? q : cnt - 1;
      int qsrow = batch * 4096 + qstart + tbase + qq;
      qi = sq[qsrow];
      const ushort* qptr = Q + (size_t)qsrow * 256 + g * 8;
      #pragma unroll
      for (int mf = 0; mf < 8; mf++) qf[mf] = *(const bf16x8*)(qptr + mf * 32);
      float2 kpv = ((const float2*)kpS)[qsrow];
      pu = kpv.x; pv = kpv.y;
    }
    #pragma unroll
    for (int i = 0; i < 16; i++) O[i] = f32x4{0.f,0.f,0.f,0.f};
    m_run = -1e9f; l_run = 0.f; u_run = 0.f; v_run = 0.f;
  };

  auto EPILOGUE = [&]() {
    if (!active) return;
    l_run += __shfl_xor(l_run, 16); l_run += __shfl_xor(l_run, 32);
    u_run += __shfl_xor(u_run, 16); u_run += __shfl_xor(u_run, 32);
    v_run += __shfl_xor(v_run, 16); v_run += __shfl_xor(v_run, 32);
    bool degen = (m_run <= -5e8f) || (l_run == 0.f);
    float rinv = degen ? 0.f : 1.0f / l_run;
    if (g == 0 && q < cnt) {
      float conf = degen ? 0.f : 1.0f;
      int row = batch * 4096 + qi;
      float fu = (u_run * rinv - pu) * conf, fv = (v_run * rinv - pv) * conf;
      ((float2*)out_flow)[row] = float2{fu, fv};
      out_conf[row] = conf;
    }
    #pragma unroll
    for (int r = 0; r < 4; r++) {
      int src = 4 * g + r;
      int qi_r = __shfl(qi, src);
      float il_r = __shfl(rinv, src);
      bool dg_r = (il_r == 0.f);
      if (src < cnt) {
        __bf16* mrow = matched + ((size_t)batch * 4096 + qi_r) * 256;
        #pragma unroll
        for (int df = 0; df < 16; df++) {
          float val = dg_r ? Vm[df * 16 + q] : O[df][r] * il_r;
          mrow[df * 16 + q] = (__bf16)val;
        }
      }
    }
  };

  if (ntile == 0) {
    for (int pp = 0; pp < npass; pp++) { PASS_INIT(pp); EPILOGUE(); }
    return;
  }

  const int total = npass * ntile;
  STAGE_LOAD(0, 0);
  STAGE_WRITE(0);
  PASS_INIT(0);
  __syncthreads();

  int i = 0, pp = 0;
  for (int it = 0; it < total; ++it) {
    const int b = it & 1;
    const bool more = (it + 1 < total);
    const int ni = (i + 1 == ntile) ? 0 : i + 1;

    if (more) STAGE_LOAD(ni, (it + 1) & 1);   // issue early (T14)

    if (active) {
      const int t = tl_t[i], ks = tl_ks[i], ke = tl_ke[i];

      // ---- QK^T from staged K (swizzled unit-major) ----
      f32x4 s0a = {0.f,0.f,0.f,0.f}, s0b = {0.f,0.f,0.f,0.f};
      f32x4 s1a = {0.f,0.f,0.f,0.f}, s1b = {0.f,0.f,0.f,0.f};
      #pragma unroll
      for (int mf = 0; mf < 8; mf += 2) {
        const int u0 = mf * 4 + g, u1 = (mf + 1) * 4 + g;
        bf16x8 ka0 = *(const bf16x8*)&Kl[b][(u0 * 32 + ((q     ) ^ (u0 & 7))) * 8];
        bf16x8 kb0 = *(const bf16x8*)&Kl[b][(u1 * 32 + ((q     ) ^ (u1 & 7))) * 8];
        bf16x8 ka1 = *(const bf16x8*)&Kl[b][(u0 * 32 + ((q + 16) ^ (u0 & 7))) * 8];
        bf16x8 kb1 = *(const bf16x8*)&Kl[b][(u1 * 32 + ((q + 16) ^ (u1 & 7))) * 8];
        s0a = MFMA16(ka0, qf[mf],     s0a);
        s0b = MFMA16(kb0, qf[mf + 1], s0b);
        s1a = MFMA16(ka1, qf[mf],     s1a);
        s1b = MFMA16(kb1, qf[mf + 1], s1b);
      }

      float aus[8], avs[8], sv[8];
      #pragma unroll
      for (int r = 0; r < 4; r++) {
        int jr = t + 4 * g + r;
        float2 cc0 = Cl[b][4 * g + r];
        aus[r] = cc0.x; avs[r] = cc0.y;
        bool val = (jr >= ks && jr < ke);
        float du = fabsf(pu - cc0.x), dv = fabsf(pv - cc0.y);
        float sr = s0a[r] + s0b[r];
        sv[r] = (val && fmaxf(du, dv) < win) ? sr * 0.0625f : -1e9f;

        int jr1 = jr + 16;
        float2 cc1 = Cl[b][16 + 4 * g + r];
        aus[4 + r] = cc1.x; avs[4 + r] = cc1.y;
        val = (jr1 >= ks && jr1 < ke);
        du = fabsf(pu - cc1.x); dv = fabsf(pv - cc1.y);
        sr = s1a[r] + s1b[r];
        sv[4 + r] = (val && fmaxf(du, dv) < win) ? sr * 0.0625f : -1e9f;
      }

      float mt = fmaxf(fmaxf(fmaxf(sv[0], sv[1]), fmaxf(sv[2], sv[3])),
                       fmaxf(fmaxf(sv[4], sv[5]), fmaxf(sv[6], sv[7])));
      mt = fmaxf(mt, __shfl_xor(mt, 16));
      mt = fmaxf(mt, __shfl_xor(mt, 32));
      if (__any(mt > m_run + 8.0f)) {       // defer-rescale (T13)
        float m_new = fmaxf(m_run, mt);
        float scale = exp2f((m_run - m_new) * LOG2E);
        l_run *= scale; u_run *= scale; v_run *= scale;
        float s_r[4];
        #pragma unroll
        for (int r = 0; r < 4; r++) s_r[r] = __shfl(scale, 4 * g + r);
        #pragma unroll
        for (int df = 0; df < 16; df++)
          #pragma unroll
          for (int r = 0; r < 4; r++) O[df][r] *= s_r[r];
        m_run = m_new;
      }

      float p[8];
      #pragma unroll
      for (int ii = 0; ii < 8; ii++) p[ii] = exp2f((sv[ii] - m_run) * LOG2E);
      #pragma unroll
      for (int ii = 0; ii < 8; ii++) {
        l_run += p[ii];
        u_run += p[ii] * aus[ii];
        v_run += p[ii] * avs[ii];
      }

      // pack P^T(C layout) -> A-operand layout via lane exchange
      uint d0 = packbf(p[0], p[1]), d1 = packbf(p[2], p[3]);
      uint d2 = packbf(p[4], p[5]), d3 = packbf(p[6], p[7]);
      int srcA = q + ((g & 1) << 5);
      int srcB = srcA + 16;
      uint x0 = (uint)__shfl((int)d0, srcA), x1 = (uint)__shfl((int)d1, srcA);
      uint x2 = (uint)__shfl((int)d0, srcB), x3 = (uint)__shfl((int)d1, srcB);
      uint y0 = (uint)__shfl((int)d2, srcA), y1 = (uint)__shfl((int)d3, srcA);
      uint y2 = (uint)__shfl((int)d2, srcB), y3 = (uint)__shfl((int)d3, srcB);
      union { uint i4[4]; bf16x8 v; } af;
      bool lo = (g < 2);
      af.i4[0] = lo ? x0 : y0; af.i4[1] = lo ? x1 : y1;
      af.i4[2] = lo ? x2 : y2; af.i4[3] = lo ? x3 : y3;

      // PV from staged VT (plane-major)
      #pragma unroll
      for (int df = 0; df < 16; df++) {
        bf16x8 vfd = *(const bf16x8*)&Vl[b][(size_t)(g * 256 + df * 16 + q) * 8];
        O[df] = MFMA16(af.v, vfd, O[df]);
      }
    }

    if (more) STAGE_WRITE((it + 1) & 1);      // vmcnt wait + LDS write (late)

    if (i == ntile - 1) {            // end of pass
      EPILOGUE();
      pp++;
      if (pp < npass) PASS_INIT(pp);
      i = 0;
    } else {
      i++;
    }
    __syncthreads();
  }
}

// ---------------------------------------------------------------------------
__global__ __launch_bounds__(256) void geo_kernel(
    const float* __restrict__ flow, const float* __restrict__ conf_in,
    const float* __restrict__ Wg1, const float* __restrict__ bg1,
    const float* __restrict__ Wg2, const float* __restrict__ bg2,
    float* __restrict__ out_geo)
{
  __shared__ float w1[32][3], b1[32], b2[32];
  __shared__ __align__(16) float w2[32][32];
  int tid = threadIdx.x;
  for (int i = tid; i < 96; i += 256) w1[i / 3][i % 3] = Wg1[i];
  if (tid < 32) { b1[tid] = bg1[tid]; b2[tid] = bg2[tid]; }
  for (int i = tid; i < 1024; i += 256) w2[i / 32][i % 32] = Wg2[i];
  __syncthreads();

  int row = blockIdx.x * 256 + tid;
  float2 f = ((const float2*)flow)[row];
  float c = conf_in[row];
  float h[32];
  #pragma unroll
  for (int j = 0; j < 32; j++) {
    float x = w1[j][0] * f.x + w1[j][1] * f.y + w1[j][2] * c + b1[j];
    h[j] = x / (1.f + __expf(-x));
  }
  #pragma unroll
  for (int o = 0; o < 32; o += 2) {
    float s0 = b2[o], s1 = b2[o + 1];
    #pragma unroll
    for (int j = 0; j < 32; j += 4) {
      f32x4 wa = *(const f32x4*)&w2[o][j];
      f32x4 wb = *(const f32x4*)&w2[o + 1][j];
      s0 += wa[0]*h[j] + wa[1]*h[j+1] + wa[2]*h[j+2] + wa[3]*h[j+3];
      s1 += wb[0]*h[j] + wb[1]*h[j+1] + wb[2]*h[j+2] + wb[3]*h[j+3];
    }
    ((float2*)out_geo)[((size_t)row * 32 + o) >> 1] = float2{s0, s1};
  }
}

// ---------------------------------------------------------------------------
extern "C" void kernel_launch(void* const* d_in, const int* in_sizes, int n_in,
                              void* d_out, int out_size, void* d_ws, size_t ws_size,
                              hipStream_t stream) {
  const float* nodes_t  = (const float*)d_in[0];
  const float* nodes_t1 = (const float*)d_in[1];
  const float* kpred    = (const float*)d_in[2];
  const float* kact     = (const float*)d_in[3];
  const float* Wq = (const float*)d_in[4];  const float* bq = (const float*)d_in[5];
  const float* Wk = (const float*)d_in[6];  const float* bk = (const float*)d_in[7];
  const float* Wv = (const float*)d_in[8];  const float* bv = (const float*)d_in[9];
  const float* Wm = (const float*)d_in[10]; const float* bm = (const float*)d_in[11];
  const float* Wg1= (const float*)d_in[12]; const float* bg1= (const float*)d_in[13];
  const float* Wg2= (const float*)d_in[14]; const float* bg2= (const float*)d_in[15];
  const int* iter = (const int*)d_in[16];

  float* out_merged = (float*)d_out;                 // 4*4096*256
  float* out_geo  = out_merged + 4 * 4096 * 256;     // 4*4096*32
  float* out_flow = out_geo + 4 * 4096 * 32;         // 4*4096*2
  float* out_conf = out_flow + 4 * 4096 * 2;         // 4*4096

  ushort* wsQ   = (ushort*)d_ws;        // bf16 4194304 el each (sorted)
  ushort* wsK   = wsQ + 4194304;        // sorted K_s
  ushort* wsVT  = wsK + 4194304;        // VT_s [4][256][4096] sorted keys
  ushort* wsM   = wsVT + 4194304;       // matched; doubles as V_s staging
  ushort* wsW   = wsM + 4194304;        // bf16 4*65536
  float*  kaS   = (float*)(wsW + 262144);   // 32768 f32
  float*  kpS   = kaS + 32768;              // 32768 f32
  float*  meanN = kpS + 32768;              // 1024
  float*  Vmean = meanN + 1024;             // 1024
  int*    hist  = (int*)(Vmean + 1024);     // 1024
  int*    strt  = hist + 1024;              // 1024
  int*    curs  = strt + 1024;              // 1024
  int*    cellpt= curs + 1024;              // 32768
  int*    sq    = cellpt + 32768;           // 16384
  int*    sk    = sq + 16384;               // 16384
  int*    invk  = sk + 16384;               // 16384
  int*    invq  = invk + 16384;             // 16384

  dim3 cg(64, 4, 1);
  cast_weights<<<cg, 256, 0, stream>>>(Wq, Wk, Wv, Wm, (__bf16*)wsW,
                                       hist, curs, meanN);
  hist_kernel<<<128, 256, 0, stream>>>(kpred, kact, hist, cellpt);
  scan_kernel<<<1, 256, 0, stream>>>(hist, strt, curs);
  scatter_kernel<<<128, 256, 0, stream>>>(kpred, kact, cellpt, curs,
                                          sq, invq, kpS, sk, invk, kaS);
  dim3 mg(16, 4, 1);
  meansum_kernel<<<mg, 256, 0, stream>>>(nodes_t1, meanN);
  vmean_kernel<<<4, 256, 0, stream>>>(meanN, Wv, bv, Vmean);

  dim3 qg(256, 2, 3);
  gemm_qkv<<<qg, 256, 0, stream>>>(nodes_t, nodes_t1, wsW, bq, bk, bv,
                                   (__bf16*)wsQ, (__bf16*)wsK, (__bf16*)wsM,
                                   invq, invk);
  dim3 tg(64, 4, 4);
  transpose_v<<<tg, 256, 0, stream>>>(wsM, wsVT);
  attn_kernel<<<400, 256, 0, stream>>>(wsQ, wsK, wsVT, kpS, iter,
                                       sq, strt, kaS, Vmean,
                                       (__bf16*)wsM, out_flow, out_conf);
  dim3 gg(256, 2, 1);
  gemm_merged<<<gg, 256, 0, stream>>>(wsM, wsW + 196608, bm, out_merged);
  geo_kernel<<<64, 256, 0, stream>>>(out_flow, out_conf, Wg1, bg1, Wg2, bg2, out_geo);
}

// Round 10
// 259.401 us; speedup vs baseline: 1.0017x; 1.0017x over previous
//
#include <hip/hip_runtime.h>
#include <hip/hip_bf16.h>

typedef unsigned short ushort;
typedef unsigned int uint;
typedef __bf16 bf16x8 __attribute__((ext_vector_type(8)));
typedef float f32x4 __attribute__((ext_vector_type(4)));
typedef ushort ushort8 __attribute__((ext_vector_type(8)));

#define LOG2E 1.4426950408889634f
#define MFMA16(a,b,c) __builtin_amdgcn_mfma_f32_16x16x32_bf16((a),(b),(c),0,0,0)
#define GLL4(src, dst) __builtin_amdgcn_global_load_lds( \
    (const __attribute__((address_space(1))) void*)(src), \
    (__attribute__((address_space(3))) void*)(dst), 4, 0, 0)

static __device__ __forceinline__ uint packbf(float lo, float hi) {
  union { __bf16 h[2]; uint u; } x;
  x.h[0] = (__bf16)lo; x.h[1] = (__bf16)hi;
  return x.u;
}
static __device__ __forceinline__ int cellof(float x) {
  int c = (int)(x * 0.015625f);           // /64
  return c < 0 ? 0 : (c > 9 ? 9 : c);
}

// ---------------------------------------------------------------------------
// cast 4 weight matrices f32->bf16; block (0,0) also zeroes counters
// ---------------------------------------------------------------------------
__global__ __launch_bounds__(256) void cast_weights(
    const float* __restrict__ W0, const float* __restrict__ W1,
    const float* __restrict__ W2, const float* __restrict__ W3,
    __bf16* __restrict__ out,
    int* __restrict__ hist, int* __restrict__ curs, float* __restrict__ meanN)
{
  if (blockIdx.x == 0 && blockIdx.y == 0) {
    int t = threadIdx.x;
    for (int i = t; i < 1024; i += 256) { hist[i] = 0; curs[i] = 0; meanN[i] = 0.f; }
  }
  const int which = blockIdx.y;
  const float* src = which == 0 ? W0 : which == 1 ? W1 : which == 2 ? W2 : W3;
  const int i = (blockIdx.x * 256 + threadIdx.x) * 4;
  f32x4 v = *(const f32x4*)(src + i);
  union { __bf16 h[4]; uint u[2]; } x;
  #pragma unroll
  for (int j = 0; j < 4; j++) x.h[j] = (__bf16)v[j];
  *(uint*)(out + (size_t)which * 65536 + i) = x.u[0];
  *(uint*)(out + (size_t)which * 65536 + i + 2) = x.u[1];
}

// ---------------------------------------------------------------------------
// histogram points into 10x10 cells. type0 = queries(kpred), type1 = keys(kact)
// ---------------------------------------------------------------------------
__global__ __launch_bounds__(256) void hist_kernel(
    const float* __restrict__ kpred, const float* __restrict__ kact,
    int* __restrict__ hist, int* __restrict__ cellpt)
{
  int p = blockIdx.x * 256 + threadIdx.x;     // 0..32767
  int type = p >> 14, idx = p & 16383;
  const float2 c = ((const float2*)(type == 0 ? kpred : kact))[idx];
  int cell = cellof(c.x) * 10 + cellof(c.y);
  int b = idx >> 12;
  atomicAdd(&hist[(type * 4 + b) * 128 + cell], 1);
  cellpt[type * 16384 + idx] = cell;
}

// ---------------------------------------------------------------------------
// exclusive scan of 8 segments x 100 cells -> start[seg][0..100], cursor copy
// ---------------------------------------------------------------------------
__global__ __launch_bounds__(256) void scan_kernel(
    const int* __restrict__ hist, int* __restrict__ strt, int* __restrict__ curs)
{
  __shared__ int sh[1024];
  int t = threadIdx.x;
  for (int i = t; i < 1024; i += 256) sh[i] = hist[i];
  __syncthreads();
  if (t < 8) {
    int run = 0;
    for (int c = 0; c < 100; c++) {
      strt[t * 128 + c] = run;
      curs[t * 128 + c] = run;
      run += sh[t * 128 + c];
    }
    strt[t * 128 + 100] = run;   // sentinel (=4096)
  }
}

// ---------------------------------------------------------------------------
// scatter: sorted index arrays, inverse perms, sorted coords (both types)
// ---------------------------------------------------------------------------
__global__ __launch_bounds__(256) void scatter_kernel(
    const float* __restrict__ kpred, const float* __restrict__ kact,
    const int* __restrict__ cellpt, int* __restrict__ curs,
    int* __restrict__ sq, int* __restrict__ invq, float* __restrict__ kpS,
    int* __restrict__ sk, int* __restrict__ invk, float* __restrict__ kaS)
{
  int p = blockIdx.x * 256 + threadIdx.x;
  int type = p >> 14, idx = p & 16383;
  int b = idx >> 12, n = idx & 4095;
  int cell = cellpt[type * 16384 + idx];
  int pos = atomicAdd(&curs[(type * 4 + b) * 128 + cell], 1);
  if (type == 0) {
    sq[b * 4096 + pos] = n;
    invq[b * 4096 + n] = pos;
    ((float2*)kpS)[b * 4096 + pos] = ((const float2*)kpred)[idx];
  } else {
    sk[b * 4096 + pos] = n;
    invk[b * 4096 + n] = pos;
    ((float2*)kaS)[b * 4096 + pos] = ((const float2*)kact)[idx];
  }
}

// ---------------------------------------------------------------------------
__global__ __launch_bounds__(256) void meansum_kernel(
    const float* __restrict__ nodes_t1, float* __restrict__ meanN)
{
  int b = blockIdx.y, chunk = blockIdx.x, c = threadIdx.x;
  const float* base = nodes_t1 + ((size_t)b * 4096 + chunk * 256) * 256 + c;
  float s = 0.f;
  for (int r = 0; r < 256; r++) s += base[(size_t)r * 256];
  atomicAdd(&meanN[b * 256 + c], s);
}

__global__ __launch_bounds__(256) void vmean_kernel(
    const float* __restrict__ meanN, const float* __restrict__ Wv,
    const float* __restrict__ bv, float* __restrict__ Vmean)
{
  __shared__ float mn[256];
  int b = blockIdx.x, d = threadIdx.x;
  mn[d] = meanN[b * 256 + d] * (1.0f / 4096.0f);
  __syncthreads();
  float s = bv[d];
  const float* w = Wv + (size_t)d * 256;
  for (int c = 0; c < 256; c++) s += mn[c] * w[c];
  Vmean[b * 256 + d] = s;
}

// ---------------------------------------------------------------------------
// fused Q/K/V projection GEMM (blockIdx.z = 0/1/2), f32 A cast in-reg.
// ALL outputs row-scattered into sorted order (coalesced 512B rows).
// ---------------------------------------------------------------------------
__global__ __launch_bounds__(256) void gemm_qkv(
    const float* __restrict__ nodes_t, const float* __restrict__ nodes_t1,
    const ushort* __restrict__ W4,
    const float* __restrict__ bq, const float* __restrict__ bk,
    const float* __restrict__ bv,
    __bf16* __restrict__ outQ, __bf16* __restrict__ outK,
    __bf16* __restrict__ outVs,
    const int* __restrict__ invq, const int* __restrict__ invk)
{
  const int z = blockIdx.z;
  const float* A = z == 0 ? nodes_t : nodes_t1;
  const ushort* W = W4 + z * 65536;
  const float* bias = z == 0 ? bq : (z == 1 ? bk : bv);
  const int* inv = z == 0 ? invq : invk;

  const int wid = threadIdx.x >> 6;
  const int lane = threadIdx.x & 63;
  const int q = lane & 15, g = lane >> 4;
  const int nb = blockIdx.x * 64 + (wid >> 1) * 32;
  const int db = blockIdx.y * 128 + (wid & 1) * 64;

  f32x4 acc[2][4];
  #pragma unroll
  for (int a = 0; a < 2; a++)
    #pragma unroll
    for (int b = 0; b < 4; b++) acc[a][b] = f32x4{0.f,0.f,0.f,0.f};

  const ushort* W0 = W + (size_t)(db + q) * 256 + g * 8;

  #pragma unroll
  for (int c0 = 0; c0 < 256; c0 += 32) {
    bf16x8 a0, a1;
    const float* Ar0 = A + (size_t)(nb + q) * 256 + g * 8 + c0;
    const float* Ar1 = A + (size_t)(nb + 16 + q) * 256 + g * 8 + c0;
    f32x4 u0 = *(const f32x4*)Ar0, u1 = *(const f32x4*)(Ar0 + 4);
    f32x4 w0 = *(const f32x4*)Ar1, w1 = *(const f32x4*)(Ar1 + 4);
    #pragma unroll
    for (int j = 0; j < 4; j++) {
      a0[j] = (__bf16)u0[j]; a0[4 + j] = (__bf16)u1[j];
      a1[j] = (__bf16)w0[j]; a1[4 + j] = (__bf16)w1[j];
    }
    #pragma unroll
    for (int df = 0; df < 4; df++) {
      bf16x8 w = *(const bf16x8*)(W0 + df * 16 * 256 + c0);
      acc[0][df] = MFMA16(a0, w, acc[0][df]);
      acc[1][df] = MFMA16(a1, w, acc[1][df]);
    }
  }
  __bf16* o = z == 0 ? outQ : (z == 1 ? outK : outVs);
  #pragma unroll
  for (int df = 0; df < 4; df++) {
    float bval = bias[db + df * 16 + q];
    #pragma unroll
    for (int nf = 0; nf < 2; nf++)
      #pragma unroll
      for (int r = 0; r < 4; r++) {
        int row = nb + nf * 16 + g * 4 + r;
        int d = db + df * 16 + q;
        float val = acc[nf][df][r] + bval;
        int pos = inv[row];
        o[((size_t)(row & ~4095) + pos) * 256 + d] = (__bf16)val;
      }
  }
}

// ---------------------------------------------------------------------------
// transpose V_s [4][4096][256] -> VT [4][256][4096], LDS 64x64 tiles
// ---------------------------------------------------------------------------
__global__ __launch_bounds__(256) void transpose_v(
    const ushort* __restrict__ Vs, ushort* __restrict__ VT)
{
  __shared__ ushort tile[64][76];
  const int b = blockIdx.z, rt = blockIdx.x, dt = blockIdx.y;
  const int tid = threadIdx.x;
  const ushort* src = Vs + ((size_t)b * 4096 + rt * 64) * 256 + dt * 64;
  #pragma unroll
  for (int i = 0; i < 2; i++) {
    int c = tid + i * 256;
    int r = c >> 3, dc = (c & 7) * 8;
    ushort8 v = *(const ushort8*)(src + (size_t)r * 256 + dc);
    #pragma unroll
    for (int j = 0; j < 8; j++) tile[r][dc + j] = v[j];
  }
  __syncthreads();
  ushort* dst = VT + ((size_t)b * 256 + dt * 64) * 4096 + rt * 64;
  #pragma unroll
  for (int i = 0; i < 2; i++) {
    int c = tid + i * 256;
    int d = c >> 3, rc = (c & 7) * 8;
    ushort8 v;
    #pragma unroll
    for (int j = 0; j < 8; j++) v[j] = tile[rc + j][d];
    *(ushort8*)(dst + (size_t)d * 4096 + rc) = v;
  }
}

// ---------------------------------------------------------------------------
// merged GEMM: bf16 A (wsM) -> f32 out
// ---------------------------------------------------------------------------
__global__ __launch_bounds__(256) void gemm_merged(
    const ushort* __restrict__ A, const ushort* __restrict__ W,
    const float* __restrict__ bias, float* __restrict__ out)
{
  const int wid = threadIdx.x >> 6;
  const int lane = threadIdx.x & 63;
  const int q = lane & 15, g = lane >> 4;
  const int nb = blockIdx.x * 64 + (wid >> 1) * 32;
  const int db = blockIdx.y * 128 + (wid & 1) * 64;

  f32x4 acc[2][4];
  #pragma unroll
  for (int a = 0; a < 2; a++)
    #pragma unroll
    for (int b = 0; b < 4; b++) acc[a][b] = f32x4{0.f,0.f,0.f,0.f};

  const ushort* W0 = W + (size_t)(db + q) * 256 + g * 8;
  const ushort* Ar0 = A + (size_t)(nb + q) * 256 + g * 8;
  const ushort* Ar1 = A + (size_t)(nb + 16 + q) * 256 + g * 8;

  #pragma unroll
  for (int c0 = 0; c0 < 256; c0 += 32) {
    bf16x8 a0 = *(const bf16x8*)(Ar0 + c0);
    bf16x8 a1 = *(const bf16x8*)(Ar1 + c0);
    #pragma unroll
    for (int df = 0; df < 4; df++) {
      bf16x8 w = *(const bf16x8*)(W0 + df * 16 * 256 + c0);
      acc[0][df] = MFMA16(a0, w, acc[0][df]);
      acc[1][df] = MFMA16(a1, w, acc[1][df]);
    }
  }
  #pragma unroll
  for (int df = 0; df < 4; df++) {
    float bval = bias[db + df * 16 + q];
    #pragma unroll
    for (int nf = 0; nf < 2; nf++)
      #pragma unroll
      for (int r = 0; r < 4; r++) {
        int row = nb + nf * 16 + g * 4 + r;
        out[(size_t)row * 256 + db + df * 16 + q] = acc[nf][df][r] + bval;
      }
  }
}

// ---------------------------------------------------------------------------
// Cooperative cell-block sparse flash attention, reg-staged coalesced tiles.
// Block = (batch, cell); 4 waves = up to 4 query-tiles sharing the 3x3 ring.
// Per key-tile: 8 coalesced global b128 loads/wave -> regs (issued early,
// T14), compute from LDS, then ds_write next tile (K XOR-swizzled unit idx).
// ---------------------------------------------------------------------------
__global__ __launch_bounds__(256, 2) void attn_kernel(
    const ushort* __restrict__ Q,    // sorted Q_s [B*4096][256]
    const ushort* __restrict__ K,    // sorted K_s [B*4096][256]
    const ushort* __restrict__ VT,   // sorted VT_s [4][256][4096]
    const float* __restrict__ kpS,   // sorted pred coords
    const int* __restrict__ iter_idx,
    const int* __restrict__ sq,      // sorted->original query index
    const int* __restrict__ strt,    // [8][128], key segs at +4*128
    const float* __restrict__ kaS,   // sorted key coords
    const float* __restrict__ Vmean,
    __bf16* __restrict__ matched,
    float* __restrict__ out_flow, float* __restrict__ out_conf)
{
  __shared__ __align__(16) ushort Kl[2][8192];   // [buf] unit-major, col^=(u&7)
  __shared__ __align__(16) ushort Vl[2][8192];   // [buf] plane-major [4][256]
  __shared__ __align__(16) float2 Cl[2][32];
  __shared__ int tl_t[132], tl_ks[132], tl_ke[132];
  __shared__ int ntile_s;

  const int tid = threadIdx.x;
  const int wid = tid >> 6, lane = tid & 63;
  const int q = lane & 15, g = lane >> 4;
  const int batch = blockIdx.x & 3;
  const int cell = blockIdx.x >> 2;

  const int qstart = strt[batch * 128 + cell];
  const int nq = strt[batch * 128 + cell + 1] - qstart;
  if (nq == 0) return;

  const int cu = cell / 10, cv = cell % 10;
  const int c0 = cv > 0 ? cv - 1 : 0, c1 = cv < 9 ? cv + 1 : 9;
  const int* kst = strt + (4 + batch) * 128;

  if (tid == 0) {
    int n = 0;
    int lo = cu > 0 ? cu - 1 : 0, hi = cu < 9 ? cu + 1 : 9;
    for (int cc = lo; cc <= hi; cc++) {
      int ks = kst[cc * 10 + c0];
      int ke = kst[cc * 10 + c1 + 1];
      for (int t = ks & ~31; t < ke; t += 32) {
        tl_t[n] = t; tl_ks[n] = ks; tl_ke[n] = ke; n++;
      }
    }
    ntile_s = n;
  }
  __syncthreads();
  const int ntile = ntile_s;

  const int idx = *iter_idx;
  const float win = (idx == 0) ? 64.0f : fmaxf(4.0f, ldexpf(32.0f, 1 - idx));

  const ushort* Kbase = K + (size_t)batch * 4096 * 256;
  const ushort* VTb = VT + (size_t)batch * 1048576;
  const float* kasf = kaS + (size_t)batch * 8192;
  const float* Vm = Vmean + batch * 256;

  const int npass = (nq + 63) >> 6;

  // staged-tile registers (coalesced loads: full 64B lines only)
  uint4 kreg[4], vreg[4];

  auto STAGE_LOAD = [&](int ti, int buf) {
    const int t = tl_t[ti];
    #pragma unroll
    for (int j = 0; j < 4; j++) {   // K: 2 full rows (512B) per load
      int r = wid * 8 + j * 2 + (lane >> 5);
      kreg[j] = *(const uint4*)(Kbase + (size_t)(t + r) * 256 + (lane & 31) * 8);
    }
    #pragma unroll
    for (int j = 0; j < 4; j++) {   // V: 16 d-rows x 64B per load
      int d = wid * 64 + j * 16 + (lane >> 2);
      vreg[j] = *(const uint4*)(VTb + (size_t)d * 4096 + t + (lane & 3) * 8);
    }
    if (wid == 0) GLL4(kasf + t * 2 + lane, &Cl[buf][0]);
  };

  auto STAGE_WRITE = [&](int buf) {
    #pragma unroll
    for (int j = 0; j < 4; j++) {   // K unit-major, column r XOR-swizzled
      int r = wid * 8 + j * 2 + (lane >> 5);
      int u = lane & 31;
      *(uint4*)&Kl[buf][(u * 32 + (r ^ (u & 7))) * 8] = kreg[j];
    }
    #pragma unroll
    for (int j = 0; j < 4; j++) {   // V plane-major (balanced as-is)
      int d = wid * 64 + j * 16 + (lane >> 2);
      *(uint4*)&Vl[buf][((lane & 3) * 256 + d) * 8] = vreg[j];
    }
  };

  // per-pass / per-wave query state
  int cnt = 0, qi = 0;
  bool active = false;
  float pu = 0.f, pv = 0.f;
  bf16x8 qf[8];
  f32x4 O[16];
  float m_run = -1e9f, l_run = 0.f, u_run = 0.f, v_run = 0.f;

  auto PASS_INIT = [&](int pp) {
    int tbase = pp * 64 + wid * 16;
    active = tbase < nq;
    cnt = active ? min(16, nq - tbase) : 0;
    if (active) {
      int qq = q < cnt ? q : cnt - 1;
      int qsrow = batch * 4096 + qstart + tbase + qq;
      qi = sq[qsrow];
      const ushort* qptr = Q + (size_t)qsrow * 256 + g * 8;
      #pragma unroll
      for (int mf = 0; mf < 8; mf++) qf[mf] = *(const bf16x8*)(qptr + mf * 32);
      float2 kpv = ((const float2*)kpS)[qsrow];
      pu = kpv.x; pv = kpv.y;
    }
    #pragma unroll
    for (int i = 0; i < 16; i++) O[i] = f32x4{0.f,0.f,0.f,0.f};
    m_run = -1e9f; l_run = 0.f; u_run = 0.f; v_run = 0.f;
  };

  auto EPILOGUE = [&]() {
    if (!active) return;
    l_run += __shfl_xor(l_run, 16); l_run += __shfl_xor(l_run, 32);
    u_run += __shfl_xor(u_run, 16); u_run += __shfl_xor(u_run, 32);
    v_run += __shfl_xor(v_run, 16); v_run += __shfl_xor(v_run, 32);
    bool degen = (m_run <= -5e8f) || (l_run == 0.f);
    float rinv = degen ? 0.f : 1.0f / l_run;
    if (g == 0 && q < cnt) {
      float conf = degen ? 0.f : 1.0f;
      int row = batch * 4096 + qi;
      float fu = (u_run * rinv - pu) * conf, fv = (v_run * rinv - pv) * conf;
      ((float2*)out_flow)[row] = float2{fu, fv};
      out_conf[row] = conf;
    }
    #pragma unroll
    for (int r = 0; r < 4; r++) {
      int src = 4 * g + r;
      int qi_r = __shfl(qi, src);
      float il_r = __shfl(rinv, src);
      bool dg_r = (il_r == 0.f);
      if (src < cnt) {
        __bf16* mrow = matched + ((size_t)batch * 4096 + qi_r) * 256;
        #pragma unroll
        for (int df = 0; df < 16; df++) {
          float val = dg_r ? Vm[df * 16 + q] : O[df][r] * il_r;
          mrow[df * 16 + q] = (__bf16)val;
        }
      }
    }
  };

  if (ntile == 0) {
    for (int pp = 0; pp < npass; pp++) { PASS_INIT(pp); EPILOGUE(); }
    return;
  }

  const int total = npass * ntile;
  STAGE_LOAD(0, 0);
  STAGE_WRITE(0);
  PASS_INIT(0);
  __syncthreads();

  int i = 0, pp = 0;
  for (int it = 0; it < total; ++it) {
    const int b = it & 1;
    const bool more = (it + 1 < total);
    const int ni = (i + 1 == ntile) ? 0 : i + 1;

    if (more) STAGE_LOAD(ni, (it + 1) & 1);   // issue early (T14)

    if (active) {
      const int t = tl_t[i], ks = tl_ks[i], ke = tl_ke[i];

      // ---- QK^T from staged K (swizzled unit-major) ----
      f32x4 s0a = {0.f,0.f,0.f,0.f}, s0b = {0.f,0.f,0.f,0.f};
      f32x4 s1a = {0.f,0.f,0.f,0.f}, s1b = {0.f,0.f,0.f,0.f};
      #pragma unroll
      for (int mf = 0; mf < 8; mf += 2) {
        const int u0 = mf * 4 + g, u1 = (mf + 1) * 4 + g;
        bf16x8 ka0 = *(const bf16x8*)&Kl[b][(u0 * 32 + ((q     ) ^ (u0 & 7))) * 8];
        bf16x8 kb0 = *(const bf16x8*)&Kl[b][(u1 * 32 + ((q     ) ^ (u1 & 7))) * 8];
        bf16x8 ka1 = *(const bf16x8*)&Kl[b][(u0 * 32 + ((q + 16) ^ (u0 & 7))) * 8];
        bf16x8 kb1 = *(const bf16x8*)&Kl[b][(u1 * 32 + ((q + 16) ^ (u1 & 7))) * 8];
        s0a = MFMA16(ka0, qf[mf],     s0a);
        s0b = MFMA16(kb0, qf[mf + 1], s0b);
        s1a = MFMA16(ka1, qf[mf],     s1a);
        s1b = MFMA16(kb1, qf[mf + 1], s1b);
      }

      float aus[8], avs[8], sv[8];
      #pragma unroll
      for (int r = 0; r < 4; r++) {
        int jr = t + 4 * g + r;
        float2 cc0 = Cl[b][4 * g + r];
        aus[r] = cc0.x; avs[r] = cc0.y;
        bool val = (jr >= ks && jr < ke);
        float du = fabsf(pu - cc0.x), dv = fabsf(pv - cc0.y);
        float sr = s0a[r] + s0b[r];
        sv[r] = (val && fmaxf(du, dv) < win) ? sr * 0.0625f : -1e9f;

        int jr1 = jr + 16;
        float2 cc1 = Cl[b][16 + 4 * g + r];
        aus[4 + r] = cc1.x; avs[4 + r] = cc1.y;
        val = (jr1 >= ks && jr1 < ke);
        du = fabsf(pu - cc1.x); dv = fabsf(pv - cc1.y);
        sr = s1a[r] + s1b[r];
        sv[4 + r] = (val && fmaxf(du, dv) < win) ? sr * 0.0625f : -1e9f;
      }

      float mt = fmaxf(fmaxf(fmaxf(sv[0], sv[1]), fmaxf(sv[2], sv[3])),
                       fmaxf(fmaxf(sv[4], sv[5]), fmaxf(sv[6], sv[7])));
      mt = fmaxf(mt, __shfl_xor(mt, 16));
      mt = fmaxf(mt, __shfl_xor(mt, 32));
      if (__any(mt > m_run + 8.0f)) {       // defer-rescale (T13)
        float m_new = fmaxf(m_run, mt);
        float scale = exp2f((m_run - m_new) * LOG2E);
        l_run *= scale; u_run *= scale; v_run *= scale;
        float s_r[4];
        #pragma unroll
        for (int r = 0; r < 4; r++) s_r[r] = __shfl(scale, 4 * g + r);
        #pragma unroll
        for (int df = 0; df < 16; df++)
          #pragma unroll
          for (int r = 0; r < 4; r++) O[df][r] *= s_r[r];
        m_run = m_new;
      }

      float p[8];
      #pragma unroll
      for (int ii = 0; ii < 8; ii++) p[ii] = exp2f((sv[ii] - m_run) * LOG2E);
      #pragma unroll
      for (int ii = 0; ii < 8; ii++) {
        l_run += p[ii];
        u_run += p[ii] * aus[ii];
        v_run += p[ii] * avs[ii];
      }

      // pack P^T(C layout) -> A-operand layout via lane exchange
      uint d0 = packbf(p[0], p[1]), d1 = packbf(p[2], p[3]);
      uint d2 = packbf(p[4], p[5]), d3 = packbf(p[6], p[7]);
      int srcA = q + ((g & 1) << 5);
      int srcB = srcA + 16;
      uint x0 = (uint)__shfl((int)d0, srcA), x1 = (uint)__shfl((int)d1, srcA);
      uint x2 = (uint)__shfl((int)d0, srcB), x3 = (uint)__shfl((int)d1, srcB);
      uint y0 = (uint)__shfl((int)d2, srcA), y1 = (uint)__shfl((int)d3, srcA);
      uint y2 = (uint)__shfl((int)d2, srcB), y3 = (uint)__shfl((int)d3, srcB);
      union { uint i4[4]; bf16x8 v; } af;
      bool lo = (g < 2);
      af.i4[0] = lo ? x0 : y0; af.i4[1] = lo ? x1 : y1;
      af.i4[2] = lo ? x2 : y2; af.i4[3] = lo ? x3 : y3;

      // PV from staged VT (plane-major)
      #pragma unroll
      for (int df = 0; df < 16; df++) {
        bf16x8 vfd = *(const bf16x8*)&Vl[b][(size_t)(g * 256 + df * 16 + q) * 8];
        O[df] = MFMA16(af.v, vfd, O[df]);
      }
    }

    if (more) STAGE_WRITE((it + 1) & 1);      // vmcnt wait + LDS write (late)

    if (i == ntile - 1) {            // end of pass
      EPILOGUE();
      pp++;
      if (pp < npass) PASS_INIT(pp);
      i = 0;
    } else {
      i++;
    }
    __syncthreads();
  }
}

// ---------------------------------------------------------------------------
__global__ __launch_bounds__(256) void geo_kernel(
    const float* __restrict__ flow, const float* __restrict__ conf_in,
    const float* __restrict__ Wg1, const float* __restrict__ bg1,
    const float* __restrict__ Wg2, const float* __restrict__ bg2,
    float* __restrict__ out_geo)
{
  __shared__ float w1[32][3], b1[32], b2[32];
  __shared__ __align__(16) float w2[32][32];
  int tid = threadIdx.x;
  for (int i = tid; i < 96; i += 256) w1[i / 3][i % 3] = Wg1[i];
  if (tid < 32) { b1[tid] = bg1[tid]; b2[tid] = bg2[tid]; }
  for (int i = tid; i < 1024; i += 256) w2[i / 32][i % 32] = Wg2[i];
  __syncthreads();

  int row = blockIdx.x * 256 + tid;
  float2 f = ((const float2*)flow)[row];
  float c = conf_in[row];
  float h[32];
  #pragma unroll
  for (int j = 0; j < 32; j++) {
    float x = w1[j][0] * f.x + w1[j][1] * f.y + w1[j][2] * c + b1[j];
    h[j] = x / (1.f + __expf(-x));
  }
  #pragma unroll
  for (int o = 0; o < 32; o += 2) {
    float s0 = b2[o], s1 = b2[o + 1];
    #pragma unroll
    for (int j = 0; j < 32; j += 4) {
      f32x4 wa = *(const f32x4*)&w2[o][j];
      f32x4 wb = *(const f32x4*)&w2[o + 1][j];
      s0 += wa[0]*h[j] + wa[1]*h[j+1] + wa[2]*h[j+2] + wa[3]*h[j+3];
      s1 += wb[0]*h[j] + wb[1]*h[j+1] + wb[2]*h[j+2] + wb[3]*h[j+3];
    }
    ((float2*)out_geo)[((size_t)row * 32 + o) >> 1] = float2{s0, s1};
  }
}

// ---------------------------------------------------------------------------
extern "C" void kernel_launch(void* const* d_in, const int* in_sizes, int n_in,
                              void* d_out, int out_size, void* d_ws, size_t ws_size,
                              hipStream_t stream) {
  const float* nodes_t  = (const float*)d_in[0];
  const float* nodes_t1 = (const float*)d_in[1];
  const float* kpred    = (const float*)d_in[2];
  const float* kact     = (const float*)d_in[3];
  const float* Wq = (const float*)d_in[4];  const float* bq = (const float*)d_in[5];
  const float* Wk = (const float*)d_in[6];  const float* bk = (const float*)d_in[7];
  const float* Wv = (const float*)d_in[8];  const float* bv = (const float*)d_in[9];
  const float* Wm = (const float*)d_in[10]; const float* bm = (const float*)d_in[11];
  const float* Wg1= (const float*)d_in[12]; const float* bg1= (const float*)d_in[13];
  const float* Wg2= (const float*)d_in[14]; const float* bg2= (const float*)d_in[15];
  const int* iter = (const int*)d_in[16];

  float* out_merged = (float*)d_out;                 // 4*4096*256
  float* out_geo  = out_merged + 4 * 4096 * 256;     // 4*4096*32
  float* out_flow = out_geo + 4 * 4096 * 32;         // 4*4096*2
  float* out_conf = out_flow + 4 * 4096 * 2;         // 4*4096

  ushort* wsQ   = (ushort*)d_ws;        // bf16 4194304 el each (sorted)
  ushort* wsK   = wsQ + 4194304;        // sorted K_s
  ushort* wsVT  = wsK + 4194304;        // VT_s [4][256][4096] sorted keys
  ushort* wsM   = wsVT + 4194304;       // matched; doubles as V_s staging
  ushort* wsW   = wsM + 4194304;        // bf16 4*65536
  float*  kaS   = (float*)(wsW + 262144);   // 32768 f32
  float*  kpS   = kaS + 32768;              // 32768 f32
  float*  meanN = kpS + 32768;              // 1024
  float*  Vmean = meanN + 1024;             // 1024
  int*    hist  = (int*)(Vmean + 1024);     // 1024
  int*    strt  = hist + 1024;              // 1024
  int*    curs  = strt + 1024;              // 1024
  int*    cellpt= curs + 1024;              // 32768
  int*    sq    = cellpt + 32768;           // 16384
  int*    sk    = sq + 16384;               // 16384
  int*    invk  = sk + 16384;               // 16384
  int*    invq  = invk + 16384;             // 16384

  dim3 cg(64, 4, 1);
  cast_weights<<<cg, 256, 0, stream>>>(Wq, Wk, Wv, Wm, (__bf16*)wsW,
                                       hist, curs, meanN);
  hist_kernel<<<128, 256, 0, stream>>>(kpred, kact, hist, cellpt);
  scan_kernel<<<1, 256, 0, stream>>>(hist, strt, curs);
  scatter_kernel<<<128, 256, 0, stream>>>(kpred, kact, cellpt, curs,
                                          sq, invq, kpS, sk, invk, kaS);
  dim3 mg(16, 4, 1);
  meansum_kernel<<<mg, 256, 0, stream>>>(nodes_t1, meanN);
  vmean_kernel<<<4, 256, 0, stream>>>(meanN, Wv, bv, Vmean);

  dim3 qg(256, 2, 3);
  gemm_qkv<<<qg, 256, 0, stream>>>(nodes_t, nodes_t1, wsW, bq, bk, bv,
                                   (__bf16*)wsQ, (__bf16*)wsK, (__bf16*)wsM,
                                   invq, invk);
  dim3 tg(64, 4, 4);
  transpose_v<<<tg, 256, 0, stream>>>(wsM, wsVT);
  attn_kernel<<<400, 256, 0, stream>>>(wsQ, wsK, wsVT, kpS, iter,
                                       sq, strt, kaS, Vmean,
                                       (__bf16*)wsM, out_flow, out_conf);
  dim3 gg(256, 2, 1);
  gemm_merged<<<gg, 256, 0, stream>>>(wsM, wsW + 196608, bm, out_merged);
  geo_kernel<<<64, 256, 0, stream>>>(out_flow, out_conf, Wg1, bg1, Wg2, bg2, out_geo);
}

// Round 11
// 205.847 us; speedup vs baseline: 1.2623x; 1.2602x over previous
//
#include <hip/hip_runtime.h>
#include <hip/hip_bf16.h>

typedef unsigned short ushort;
typedef unsigned int uint;
typedef __bf16 bf16x8 __attribute__((ext_vector_type(8)));
typedef float f32x4 __attribute__((ext_vector_type(4)));
typedef ushort ushort8 __attribute__((ext_vector_type(8)));

#define LOG2E 1.4426950408889634f
#define MFMA16(a,b,c) __builtin_amdgcn_mfma_f32_16x16x32_bf16((a),(b),(c),0,0,0)
#define GLL16(src, dst) __builtin_amdgcn_global_load_lds( \
    (const __attribute__((address_space(1))) void*)(src), \
    (__attribute__((address_space(3))) void*)(dst), 16, 0, 0)
#define GLL4(src, dst) __builtin_amdgcn_global_load_lds( \
    (const __attribute__((address_space(1))) void*)(src), \
    (__attribute__((address_space(3))) void*)(dst), 4, 0, 0)

static __device__ __forceinline__ uint packbf(float lo, float hi) {
  union { __bf16 h[2]; uint u; } x;
  x.h[0] = (__bf16)lo; x.h[1] = (__bf16)hi;
  return x.u;
}
static __device__ __forceinline__ int cellof(float x) {
  int c = (int)(x * 0.015625f);           // /64
  return c < 0 ? 0 : (c > 9 ? 9 : c);
}

// ---------------------------------------------------------------------------
// cast 4 weight matrices f32->bf16; block (0,0) also zeroes counters
// ---------------------------------------------------------------------------
__global__ __launch_bounds__(256) void cast_weights(
    const float* __restrict__ W0, const float* __restrict__ W1,
    const float* __restrict__ W2, const float* __restrict__ W3,
    __bf16* __restrict__ out,
    int* __restrict__ hist, int* __restrict__ curs, float* __restrict__ meanN)
{
  if (blockIdx.x == 0 && blockIdx.y == 0) {
    int t = threadIdx.x;
    for (int i = t; i < 1024; i += 256) { hist[i] = 0; curs[i] = 0; meanN[i] = 0.f; }
  }
  const int which = blockIdx.y;
  const float* src = which == 0 ? W0 : which == 1 ? W1 : which == 2 ? W2 : W3;
  const int i = (blockIdx.x * 256 + threadIdx.x) * 4;
  f32x4 v = *(const f32x4*)(src + i);
  union { __bf16 h[4]; uint u[2]; } x;
  #pragma unroll
  for (int j = 0; j < 4; j++) x.h[j] = (__bf16)v[j];
  *(uint*)(out + (size_t)which * 65536 + i) = x.u[0];
  *(uint*)(out + (size_t)which * 65536 + i + 2) = x.u[1];
}

// ---------------------------------------------------------------------------
// cast nodes f32 -> bf16 (y=0: nodes_t, y=1: nodes_t1)
// ---------------------------------------------------------------------------
__global__ __launch_bounds__(256) void cast_nodes(
    const float* __restrict__ n0, const float* __restrict__ n1,
    __bf16* __restrict__ o0, __bf16* __restrict__ o1)
{
  const float* s = blockIdx.y ? n1 : n0;
  __bf16* o = blockIdx.y ? o1 : o0;
  const int i = (blockIdx.x * 256 + threadIdx.x) * 4;
  f32x4 v = *(const f32x4*)(s + i);
  union { __bf16 h[4]; uint u[2]; } x;
  #pragma unroll
  for (int j = 0; j < 4; j++) x.h[j] = (__bf16)v[j];
  *(uint*)(o + i) = x.u[0];
  *(uint*)(o + i + 2) = x.u[1];
}

// ---------------------------------------------------------------------------
// histogram points into 10x10 cells. type0 = queries(kpred), type1 = keys(kact)
// ---------------------------------------------------------------------------
__global__ __launch_bounds__(256) void hist_kernel(
    const float* __restrict__ kpred, const float* __restrict__ kact,
    int* __restrict__ hist, int* __restrict__ cellpt)
{
  int p = blockIdx.x * 256 + threadIdx.x;     // 0..32767
  int type = p >> 14, idx = p & 16383;
  const float2 c = ((const float2*)(type == 0 ? kpred : kact))[idx];
  int cell = cellof(c.x) * 10 + cellof(c.y);
  int b = idx >> 12;
  atomicAdd(&hist[(type * 4 + b) * 128 + cell], 1);
  cellpt[type * 16384 + idx] = cell;
}

// ---------------------------------------------------------------------------
// exclusive scan of 8 segments x 100 cells -> start[seg][0..100], cursor copy
// ---------------------------------------------------------------------------
__global__ __launch_bounds__(256) void scan_kernel(
    const int* __restrict__ hist, int* __restrict__ strt, int* __restrict__ curs)
{
  __shared__ int sh[1024];
  int t = threadIdx.x;
  for (int i = t; i < 1024; i += 256) sh[i] = hist[i];
  __syncthreads();
  if (t < 8) {
    int run = 0;
    for (int c = 0; c < 100; c++) {
      strt[t * 128 + c] = run;
      curs[t * 128 + c] = run;
      run += sh[t * 128 + c];
    }
    strt[t * 128 + 100] = run;   // sentinel (=4096)
  }
}

// ---------------------------------------------------------------------------
// scatter: sorted index arrays, inverse perms, sorted coords (both types)
// ---------------------------------------------------------------------------
__global__ __launch_bounds__(256) void scatter_kernel(
    const float* __restrict__ kpred, const float* __restrict__ kact,
    const int* __restrict__ cellpt, int* __restrict__ curs,
    int* __restrict__ sq, int* __restrict__ invq, float* __restrict__ kpS,
    int* __restrict__ sk, int* __restrict__ invk, float* __restrict__ kaS)
{
  int p = blockIdx.x * 256 + threadIdx.x;
  int type = p >> 14, idx = p & 16383;
  int b = idx >> 12, n = idx & 4095;
  int cell = cellpt[type * 16384 + idx];
  int pos = atomicAdd(&curs[(type * 4 + b) * 128 + cell], 1);
  if (type == 0) {
    sq[b * 4096 + pos] = n;
    invq[b * 4096 + n] = pos;
    ((float2*)kpS)[b * 4096 + pos] = ((const float2*)kpred)[idx];
  } else {
    sk[b * 4096 + pos] = n;
    invk[b * 4096 + n] = pos;
    ((float2*)kaS)[b * 4096 + pos] = ((const float2*)kact)[idx];
  }
}

// ---------------------------------------------------------------------------
__global__ __launch_bounds__(256) void meansum_kernel(
    const float* __restrict__ nodes_t1, float* __restrict__ meanN)
{
  int b = blockIdx.y, chunk = blockIdx.x, c = threadIdx.x;
  const float* base = nodes_t1 + ((size_t)b * 4096 + chunk * 256) * 256 + c;
  float s = 0.f;
  for (int r = 0; r < 256; r++) s += base[(size_t)r * 256];
  atomicAdd(&meanN[b * 256 + c], s);
}

__global__ __launch_bounds__(256) void vmean_kernel(
    const float* __restrict__ meanN, const float* __restrict__ Wv,
    const float* __restrict__ bv, float* __restrict__ Vmean)
{
  __shared__ float mn[256];
  int b = blockIdx.x, d = threadIdx.x;
  mn[d] = meanN[b * 256 + d] * (1.0f / 4096.0f);
  __syncthreads();
  float s = bv[d];
  const float* w = Wv + (size_t)d * 256;
  for (int c = 0; c < 256; c++) s += mn[c] * w[c];
  Vmean[b * 256 + d] = s;
}

// ---------------------------------------------------------------------------
// Q/K/V projection GEMM, bf16 A. z=0: Q only. z=1: K and V fused (A read once).
// Outputs row-scattered into sorted order (coalesced 512B rows).
// ---------------------------------------------------------------------------
__global__ __launch_bounds__(256) void gemm_qkv(
    const ushort* __restrict__ A0, const ushort* __restrict__ A1,
    const ushort* __restrict__ W4,
    const float* __restrict__ bq, const float* __restrict__ bk,
    const float* __restrict__ bv,
    __bf16* __restrict__ outQ, __bf16* __restrict__ outK,
    __bf16* __restrict__ outVs,
    const int* __restrict__ invq, const int* __restrict__ invk)
{
  const int z = blockIdx.z;
  const ushort* A = z == 0 ? A0 : A1;
  const ushort* Wa = z == 0 ? W4 : W4 + 65536;       // Wq or Wk
  const ushort* Wb = W4 + 131072;                    // Wv (z=1 only)
  const int* inv = z == 0 ? invq : invk;

  const int wid = threadIdx.x >> 6;
  const int lane = threadIdx.x & 63;
  const int q = lane & 15, g = lane >> 4;
  const int nb = blockIdx.x * 64 + (wid >> 1) * 32;
  const int db = blockIdx.y * 128 + (wid & 1) * 64;

  f32x4 acc[2][4], accv[2][4];
  #pragma unroll
  for (int a = 0; a < 2; a++)
    #pragma unroll
    for (int b = 0; b < 4; b++) {
      acc[a][b] = f32x4{0.f,0.f,0.f,0.f};
      accv[a][b] = f32x4{0.f,0.f,0.f,0.f};
    }

  const ushort* Wa0 = Wa + (size_t)(db + q) * 256 + g * 8;
  const ushort* Wb0 = Wb + (size_t)(db + q) * 256 + g * 8;
  const ushort* Ar0 = A + (size_t)(nb + q) * 256 + g * 8;
  const ushort* Ar1 = A + (size_t)(nb + 16 + q) * 256 + g * 8;

  #pragma unroll
  for (int c0 = 0; c0 < 256; c0 += 32) {
    bf16x8 a0 = *(const bf16x8*)(Ar0 + c0);
    bf16x8 a1 = *(const bf16x8*)(Ar1 + c0);
    #pragma unroll
    for (int df = 0; df < 4; df++) {
      bf16x8 w = *(const bf16x8*)(Wa0 + df * 16 * 256 + c0);
      acc[0][df] = MFMA16(a0, w, acc[0][df]);
      acc[1][df] = MFMA16(a1, w, acc[1][df]);
    }
    if (z == 1) {
      #pragma unroll
      for (int df = 0; df < 4; df++) {
        bf16x8 w = *(const bf16x8*)(Wb0 + df * 16 * 256 + c0);
        accv[0][df] = MFMA16(a0, w, accv[0][df]);
        accv[1][df] = MFMA16(a1, w, accv[1][df]);
      }
    }
  }
  const float* biasA = z == 0 ? bq : bk;
  __bf16* oA = z == 0 ? outQ : outK;
  #pragma unroll
  for (int df = 0; df < 4; df++) {
    float ba = biasA[db + df * 16 + q];
    float bb = bv[db + df * 16 + q];
    #pragma unroll
    for (int nf = 0; nf < 2; nf++)
      #pragma unroll
      for (int r = 0; r < 4; r++) {
        int row = nb + nf * 16 + g * 4 + r;
        int d = db + df * 16 + q;
        int pos = inv[row];
        size_t orow = (size_t)(row & ~4095) + pos;
        oA[orow * 256 + d] = (__bf16)(acc[nf][df][r] + ba);
        if (z == 1)
          outVs[orow * 256 + d] = (__bf16)(accv[nf][df][r] + bb);
      }
  }
}

// ---------------------------------------------------------------------------
// transpose V_s [4][4096][256] -> VT [4][256][4096], LDS 64x64 tiles
// ---------------------------------------------------------------------------
__global__ __launch_bounds__(256) void transpose_v(
    const ushort* __restrict__ Vs, ushort* __restrict__ VT)
{
  __shared__ ushort tile[64][76];
  const int b = blockIdx.z, rt = blockIdx.x, dt = blockIdx.y;
  const int tid = threadIdx.x;
  const ushort* src = Vs + ((size_t)b * 4096 + rt * 64) * 256 + dt * 64;
  #pragma unroll
  for (int i = 0; i < 2; i++) {
    int c = tid + i * 256;
    int r = c >> 3, dc = (c & 7) * 8;
    ushort8 v = *(const ushort8*)(src + (size_t)r * 256 + dc);
    #pragma unroll
    for (int j = 0; j < 8; j++) tile[r][dc + j] = v[j];
  }
  __syncthreads();
  ushort* dst = VT + ((size_t)b * 256 + dt * 64) * 4096 + rt * 64;
  #pragma unroll
  for (int i = 0; i < 2; i++) {
    int c = tid + i * 256;
    int d = c >> 3, rc = (c & 7) * 8;
    ushort8 v;
    #pragma unroll
    for (int j = 0; j < 8; j++) v[j] = tile[rc + j][d];
    *(ushort8*)(dst + (size_t)d * 4096 + rc) = v;
  }
}

// ---------------------------------------------------------------------------
// merged GEMM: bf16 A (wsM) -> f32 out
// ---------------------------------------------------------------------------
__global__ __launch_bounds__(256) void gemm_merged(
    const ushort* __restrict__ A, const ushort* __restrict__ W,
    const float* __restrict__ bias, float* __restrict__ out)
{
  const int wid = threadIdx.x >> 6;
  const int lane = threadIdx.x & 63;
  const int q = lane & 15, g = lane >> 4;
  const int nb = blockIdx.x * 64 + (wid >> 1) * 32;
  const int db = blockIdx.y * 128 + (wid & 1) * 64;

  f32x4 acc[2][4];
  #pragma unroll
  for (int a = 0; a < 2; a++)
    #pragma unroll
    for (int b = 0; b < 4; b++) acc[a][b] = f32x4{0.f,0.f,0.f,0.f};

  const ushort* W0 = W + (size_t)(db + q) * 256 + g * 8;
  const ushort* Ar0 = A + (size_t)(nb + q) * 256 + g * 8;
  const ushort* Ar1 = A + (size_t)(nb + 16 + q) * 256 + g * 8;

  #pragma unroll
  for (int c0 = 0; c0 < 256; c0 += 32) {
    bf16x8 a0 = *(const bf16x8*)(Ar0 + c0);
    bf16x8 a1 = *(const bf16x8*)(Ar1 + c0);
    #pragma unroll
    for (int df = 0; df < 4; df++) {
      bf16x8 w = *(const bf16x8*)(W0 + df * 16 * 256 + c0);
      acc[0][df] = MFMA16(a0, w, acc[0][df]);
      acc[1][df] = MFMA16(a1, w, acc[1][df]);
    }
  }
  #pragma unroll
  for (int df = 0; df < 4; df++) {
    float bval = bias[db + df * 16 + q];
    #pragma unroll
    for (int nf = 0; nf < 2; nf++)
      #pragma unroll
      for (int r = 0; r < 4; r++) {
        int row = nb + nf * 16 + g * 4 + r;
        out[(size_t)row * 256 + db + df * 16 + q] = acc[nf][df][r] + bval;
      }
  }
}

// ---------------------------------------------------------------------------
// Cooperative cell-block sparse flash attention (R8 structure, best known).
// Block = (batch, cell) via bijective XCD swizzle: each XCD owns a contiguous
// half-batch (working set ~3MB -> L2-resident staging).
// ---------------------------------------------------------------------------
__global__ __launch_bounds__(256, 2) void attn_kernel(
    const ushort* __restrict__ Q,    // sorted Q_s [B*4096][256]
    const ushort* __restrict__ K,    // sorted K_s [B*4096][256]
    const ushort* __restrict__ VT,   // sorted VT_s [4][256][4096]
    const float* __restrict__ kpS,   // sorted pred coords
    const int* __restrict__ iter_idx,
    const int* __restrict__ sq,      // sorted->original query index
    const int* __restrict__ strt,    // [8][128], key segs at +4*128
    const float* __restrict__ kaS,   // sorted key coords
    const float* __restrict__ Vmean,
    __bf16* __restrict__ matched,
    float* __restrict__ out_flow, float* __restrict__ out_conf)
{
  __shared__ __align__(16) ushort Kl[2][8192];   // [buf][(u*32+r)*8]
  __shared__ __align__(16) ushort Vl[2][8192];   // [buf][(plane*256+d)*8]
  __shared__ __align__(16) float2 Cl[2][32];
  __shared__ int tl_t[132], tl_ks[132], tl_ke[132];
  __shared__ int ntile_s;

  const int tid = threadIdx.x;
  const int wid = tid >> 6, lane = tid & 63;
  const int q = lane & 15, g = lane >> 4;
  // bijective XCD swizzle: orig%8 -> XCD; give each XCD 50 consecutive wgids
  const int orig = blockIdx.x;
  const int wgid = (orig & 7) * 50 + (orig >> 3);
  const int batch = wgid / 100;
  const int cell = wgid % 100;

  const int qstart = strt[batch * 128 + cell];
  const int nq = strt[batch * 128 + cell + 1] - qstart;
  if (nq == 0) return;

  const int cu = cell / 10, cv = cell % 10;
  const int c0 = cv > 0 ? cv - 1 : 0, c1 = cv < 9 ? cv + 1 : 9;
  const int* kst = strt + (4 + batch) * 128;

  if (tid == 0) {
    int n = 0;
    int lo = cu > 0 ? cu - 1 : 0, hi = cu < 9 ? cu + 1 : 9;
    for (int cc = lo; cc <= hi; cc++) {
      int ks = kst[cc * 10 + c0];
      int ke = kst[cc * 10 + c1 + 1];
      for (int t = ks & ~31; t < ke; t += 32) {
        tl_t[n] = t; tl_ks[n] = ks; tl_ke[n] = ke; n++;
      }
    }
    ntile_s = n;
  }
  __syncthreads();
  const int ntile = ntile_s;

  const int idx = *iter_idx;
  const float win = (idx == 0) ? 64.0f : fmaxf(4.0f, ldexpf(32.0f, 1 - idx));

  const ushort* Kbase = K + (size_t)batch * 4096 * 256;
  const ushort* VTb = VT + (size_t)batch * 1048576;
  const float* kasf = kaS + (size_t)batch * 8192;
  const float* Vm = Vmean + batch * 256;

  const int npass = (nq + 63) >> 6;

  // cooperative stage of tile list entry `ti` into buffer `b`
  auto STAGE = [&](int ti, int b) {
    const int t = tl_t[ti];
    #pragma unroll
    for (int j = 0; j < 4; j++) {
      int n = wid * 256 + j * 64 + lane;
      int r = n & 31, u = n >> 5;
      GLL16(Kbase + (size_t)(t + r) * 256 + u * 8,
            &Kl[b][(size_t)(wid * 256 + j * 64) * 8]);
    }
    #pragma unroll
    for (int j = 0; j < 4; j++) {
      int n = wid * 256 + j * 64 + lane;
      int pl = n >> 8, d = n & 255;
      GLL16(VTb + (size_t)d * 4096 + t + pl * 8,
            &Vl[b][(size_t)(wid * 256 + j * 64) * 8]);
    }
    if (wid == 0) GLL4(kasf + t * 2 + lane, &Cl[b][0]);
  };

  // per-pass / per-wave query state
  int cnt = 0, qi = 0;
  bool active = false;
  float pu = 0.f, pv = 0.f;
  bf16x8 qf[8];
  f32x4 O[16];
  float m_run = -1e9f, l_run = 0.f, u_run = 0.f, v_run = 0.f;

  auto PASS_INIT = [&](int pp) {
    int tbase = pp * 64 + wid * 16;
    active = tbase < nq;
    cnt = active ? min(16, nq - tbase) : 0;
    if (active) {
      int qq = q < cnt ? q : cnt - 1;
      int qsrow = batch * 4096 + qstart + tbase + qq;
      qi = sq[qsrow];
      const ushort* qptr = Q + (size_t)qsrow * 256 + g * 8;
      #pragma unroll
      for (int mf = 0; mf < 8; mf++) qf[mf] = *(const bf16x8*)(qptr + mf * 32);
      float2 kpv = ((const float2*)kpS)[qsrow];
      pu = kpv.x; pv = kpv.y;
    }
    #pragma unroll
    for (int i = 0; i < 16; i++) O[i] = f32x4{0.f,0.f,0.f,0.f};
    m_run = -1e9f; l_run = 0.f; u_run = 0.f; v_run = 0.f;
  };

  auto EPILOGUE = [&]() {
    if (!active) return;
    l_run += __shfl_xor(l_run, 16); l_run += __shfl_xor(l_run, 32);
    u_run += __shfl_xor(u_run, 16); u_run += __shfl_xor(u_run, 32);
    v_run += __shfl_xor(v_run, 16); v_run += __shfl_xor(v_run, 32);
    bool degen = (m_run <= -5e8f) || (l_run == 0.f);
    float rinv = degen ? 0.f : 1.0f / l_run;
    if (g == 0 && q < cnt) {
      float conf = degen ? 0.f : 1.0f;
      int row = batch * 4096 + qi;
      float fu = (u_run * rinv - pu) * conf, fv = (v_run * rinv - pv) * conf;
      ((float2*)out_flow)[row] = float2{fu, fv};
      out_conf[row] = conf;
    }
    #pragma unroll
    for (int r = 0; r < 4; r++) {
      int src = 4 * g + r;
      int qi_r = __shfl(qi, src);
      float il_r = __shfl(rinv, src);
      bool dg_r = (il_r == 0.f);
      if (src < cnt) {
        __bf16* mrow = matched + ((size_t)batch * 4096 + qi_r) * 256;
        #pragma unroll
        for (int df = 0; df < 16; df++) {
          float val = dg_r ? Vm[df * 16 + q] : O[df][r] * il_r;
          mrow[df * 16 + q] = (__bf16)val;
        }
      }
    }
  };

  if (ntile == 0) {
    for (int pp = 0; pp < npass; pp++) { PASS_INIT(pp); EPILOGUE(); }
    return;
  }

  const int total = npass * ntile;
  STAGE(0, 0);
  PASS_INIT(0);

  int i = 0, pp = 0;
  for (int it = 0; it < total; ++it) {
    __syncthreads();   // stage(it) done; everyone's compute(it-1) done
    if (it + 1 < total) {
      int ni = (i + 1 == ntile) ? 0 : i + 1;
      STAGE(ni, (it + 1) & 1);
    }
    const int b = it & 1;

    if (active) {
      const int t = tl_t[i], ks = tl_ks[i], ke = tl_ke[i];

      // ---- QK^T from staged K ----
      f32x4 s0a = {0.f,0.f,0.f,0.f}, s0b = {0.f,0.f,0.f,0.f};
      f32x4 s1a = {0.f,0.f,0.f,0.f}, s1b = {0.f,0.f,0.f,0.f};
      #pragma unroll
      for (int mf = 0; mf < 8; mf += 2) {
        bf16x8 ka0 = *(const bf16x8*)&Kl[b][(size_t)(((mf    ) * 4 + g) * 32 + q     ) * 8];
        bf16x8 kb0 = *(const bf16x8*)&Kl[b][(size_t)(((mf + 1) * 4 + g) * 32 + q     ) * 8];
        bf16x8 ka1 = *(const bf16x8*)&Kl[b][(size_t)(((mf    ) * 4 + g) * 32 + q + 16) * 8];
        bf16x8 kb1 = *(const bf16x8*)&Kl[b][(size_t)(((mf + 1) * 4 + g) * 32 + q + 16) * 8];
        s0a = MFMA16(ka0, qf[mf],     s0a);
        s0b = MFMA16(kb0, qf[mf + 1], s0b);
        s1a = MFMA16(ka1, qf[mf],     s1a);
        s1b = MFMA16(kb1, qf[mf + 1], s1b);
      }

      float aus[8], avs[8], sv[8];
      #pragma unroll
      for (int r = 0; r < 4; r++) {
        int jr = t + 4 * g + r;
        float2 cc0 = Cl[b][4 * g + r];
        aus[r] = cc0.x; avs[r] = cc0.y;
        bool val = (jr >= ks && jr < ke);
        float du = fabsf(pu - cc0.x), dv = fabsf(pv - cc0.y);
        float sr = s0a[r] + s0b[r];
        sv[r] = (val && fmaxf(du, dv) < win) ? sr * 0.0625f : -1e9f;

        int jr1 = jr + 16;
        float2 cc1 = Cl[b][16 + 4 * g + r];
        aus[4 + r] = cc1.x; avs[4 + r] = cc1.y;
        val = (jr1 >= ks && jr1 < ke);
        du = fabsf(pu - cc1.x); dv = fabsf(pv - cc1.y);
        sr = s1a[r] + s1b[r];
        sv[4 + r] = (val && fmaxf(du, dv) < win) ? sr * 0.0625f : -1e9f;
      }

      float mt = fmaxf(fmaxf(fmaxf(sv[0], sv[1]), fmaxf(sv[2], sv[3])),
                       fmaxf(fmaxf(sv[4], sv[5]), fmaxf(sv[6], sv[7])));
      mt = fmaxf(mt, __shfl_xor(mt, 16));
      mt = fmaxf(mt, __shfl_xor(mt, 32));
      if (__any(mt > m_run + 8.0f)) {       // defer-rescale (T13)
        float m_new = fmaxf(m_run, mt);
        float scale = exp2f((m_run - m_new) * LOG2E);
        l_run *= scale; u_run *= scale; v_run *= scale;
        float s_r[4];
        #pragma unroll
        for (int r = 0; r < 4; r++) s_r[r] = __shfl(scale, 4 * g + r);
        #pragma unroll
        for (int df = 0; df < 16; df++)
          #pragma unroll
          for (int r = 0; r < 4; r++) O[df][r] *= s_r[r];
        m_run = m_new;
      }

      float p[8];
      #pragma unroll
      for (int ii = 0; ii < 8; ii++) p[ii] = exp2f((sv[ii] - m_run) * LOG2E);
      #pragma unroll
      for (int ii = 0; ii < 8; ii++) {
        l_run += p[ii];
        u_run += p[ii] * aus[ii];
        v_run += p[ii] * avs[ii];
      }

      // pack P^T(C layout) -> A-operand layout via lane exchange
      uint d0 = packbf(p[0], p[1]), d1 = packbf(p[2], p[3]);
      uint d2 = packbf(p[4], p[5]), d3 = packbf(p[6], p[7]);
      int srcA = q + ((g & 1) << 5);
      int srcB = srcA + 16;
      uint x0 = (uint)__shfl((int)d0, srcA), x1 = (uint)__shfl((int)d1, srcA);
      uint x2 = (uint)__shfl((int)d0, srcB), x3 = (uint)__shfl((int)d1, srcB);
      uint y0 = (uint)__shfl((int)d2, srcA), y1 = (uint)__shfl((int)d3, srcA);
      uint y2 = (uint)__shfl((int)d2, srcB), y3 = (uint)__shfl((int)d3, srcB);
      union { uint i4[4]; bf16x8 v; } af;
      bool lo = (g < 2);
      af.i4[0] = lo ? x0 : y0; af.i4[1] = lo ? x1 : y1;
      af.i4[2] = lo ? x2 : y2; af.i4[3] = lo ? x3 : y3;

      // PV from staged VT (plane-major)
      #pragma unroll
      for (int df = 0; df < 16; df++) {
        bf16x8 vfd = *(const bf16x8*)&Vl[b][(size_t)(g * 256 + df * 16 + q) * 8];
        O[df] = MFMA16(af.v, vfd, O[df]);
      }
    }

    if (i == ntile - 1) {            // end of pass
      EPILOGUE();
      pp++;
      if (pp < npass) PASS_INIT(pp);
      i = 0;
    } else {
      i++;
    }
  }
}

// ---------------------------------------------------------------------------
__global__ __launch_bounds__(256) void geo_kernel(
    const float* __restrict__ flow, const float* __restrict__ conf_in,
    const float* __restrict__ Wg1, const float* __restrict__ bg1,
    const float* __restrict__ Wg2, const float* __restrict__ bg2,
    float* __restrict__ out_geo)
{
  __shared__ float w1[32][3], b1[32], b2[32];
  __shared__ __align__(16) float w2[32][32];
  int tid = threadIdx.x;
  for (int i = tid; i < 96; i += 256) w1[i / 3][i % 3] = Wg1[i];
  if (tid < 32) { b1[tid] = bg1[tid]; b2[tid] = bg2[tid]; }
  for (int i = tid; i < 1024; i += 256) w2[i / 32][i % 32] = Wg2[i];
  __syncthreads();

  int row = blockIdx.x * 256 + tid;
  float2 f = ((const float2*)flow)[row];
  float c = conf_in[row];
  float h[32];
  #pragma unroll
  for (int j = 0; j < 32; j++) {
    float x = w1[j][0] * f.x + w1[j][1] * f.y + w1[j][2] * c + b1[j];
    h[j] = x / (1.f + __expf(-x));
  }
  #pragma unroll
  for (int o = 0; o < 32; o += 2) {
    float s0 = b2[o], s1 = b2[o + 1];
    #pragma unroll
    for (int j = 0; j < 32; j += 4) {
      f32x4 wa = *(const f32x4*)&w2[o][j];
      f32x4 wb = *(const f32x4*)&w2[o + 1][j];
      s0 += wa[0]*h[j] + wa[1]*h[j+1] + wa[2]*h[j+2] + wa[3]*h[j+3];
      s1 += wb[0]*h[j] + wb[1]*h[j+1] + wb[2]*h[j+2] + wb[3]*h[j+3];
    }
    ((float2*)out_geo)[((size_t)row * 32 + o) >> 1] = float2{s0, s1};
  }
}

// ---------------------------------------------------------------------------
extern "C" void kernel_launch(void* const* d_in, const int* in_sizes, int n_in,
                              void* d_out, int out_size, void* d_ws, size_t ws_size,
                              hipStream_t stream) {
  const float* nodes_t  = (const float*)d_in[0];
  const float* nodes_t1 = (const float*)d_in[1];
  const float* kpred    = (const float*)d_in[2];
  const float* kact     = (const float*)d_in[3];
  const float* Wq = (const float*)d_in[4];  const float* bq = (const float*)d_in[5];
  const float* Wk = (const float*)d_in[6];  const float* bk = (const float*)d_in[7];
  const float* Wv = (const float*)d_in[8];  const float* bv = (const float*)d_in[9];
  const float* Wm = (const float*)d_in[10]; const float* bm = (const float*)d_in[11];
  const float* Wg1= (const float*)d_in[12]; const float* bg1= (const float*)d_in[13];
  const float* Wg2= (const float*)d_in[14]; const float* bg2= (const float*)d_in[15];
  const int* iter = (const int*)d_in[16];

  float* out_merged = (float*)d_out;                 // 4*4096*256
  float* out_geo  = out_merged + 4 * 4096 * 32 * 8;  // 4*4096*256 elements
  out_geo = out_merged + 4 * 4096 * 256;
  float* out_flow = out_geo + 4 * 4096 * 32;         // 4*4096*2
  float* out_conf = out_flow + 4 * 4096 * 2;         // 4*4096

  ushort* wsQ   = (ushort*)d_ws;        // bf16 4194304 el each (sorted)
  ushort* wsK   = wsQ + 4194304;        // sorted K_s
  ushort* wsVT  = wsK + 4194304;        // VT_s [4][256][4096] sorted keys
  ushort* wsM   = wsVT + 4194304;       // matched; doubles as V_s staging
  ushort* wsW   = wsM + 4194304;        // bf16 4*65536
  float*  kaS   = (float*)(wsW + 262144);   // 32768 f32
  float*  kpS   = kaS + 32768;              // 32768 f32
  float*  meanN = kpS + 32768;              // 1024
  float*  Vmean = meanN + 1024;             // 1024
  int*    hist  = (int*)(Vmean + 1024);     // 1024
  int*    strt  = hist + 1024;              // 1024
  int*    curs  = strt + 1024;              // 1024
  int*    cellpt= curs + 1024;              // 32768
  int*    sq    = cellpt + 32768;           // 16384
  int*    sk    = sq + 16384;               // 16384
  int*    invk  = sk + 16384;               // 16384
  int*    invq  = invk + 16384;             // 16384
  ushort* wsA0  = (ushort*)(invq + 16384);  // bf16 nodes_t   4194304
  ushort* wsA1  = wsA0 + 4194304;           // bf16 nodes_t1  4194304

  dim3 cg(64, 4, 1);
  cast_weights<<<cg, 256, 0, stream>>>(Wq, Wk, Wv, Wm, (__bf16*)wsW,
                                       hist, curs, meanN);
  dim3 ng(4096, 2, 1);
  cast_nodes<<<ng, 256, 0, stream>>>(nodes_t, nodes_t1,
                                     (__bf16*)wsA0, (__bf16*)wsA1);
  hist_kernel<<<128, 256, 0, stream>>>(kpred, kact, hist, cellpt);
  scan_kernel<<<1, 256, 0, stream>>>(hist, strt, curs);
  scatter_kernel<<<128, 256, 0, stream>>>(kpred, kact, cellpt, curs,
                                          sq, invq, kpS, sk, invk, kaS);
  dim3 mg(16, 4, 1);
  meansum_kernel<<<mg, 256, 0, stream>>>(nodes_t1, meanN);
  vmean_kernel<<<4, 256, 0, stream>>>(meanN, Wv, bv, Vmean);

  dim3 qg(256, 2, 2);
  gemm_qkv<<<qg, 256, 0, stream>>>(wsA0, wsA1, wsW, bq, bk, bv,
                                   (__bf16*)wsQ, (__bf16*)wsK, (__bf16*)wsM,
                                   invq, invk);
  dim3 tg(64, 4, 4);
  transpose_v<<<tg, 256, 0, stream>>>(wsM, wsVT);
  attn_kernel<<<400, 256, 0, stream>>>(wsQ, wsK, wsVT, kpS, iter,
                                       sq, strt, kaS, Vmean,
                                       (__bf16*)wsM, out_flow, out_conf);
  dim3 gg(256, 2, 1);
  gemm_merged<<<gg, 256, 0, stream>>>(wsM, wsW + 196608, bm, out_merged);
  geo_kernel<<<64, 256, 0, stream>>>(out_flow, out_conf, Wg1, bg1, Wg2, bg2, out_geo);
}

// Round 13
// 179.937 us; speedup vs baseline: 1.4441x; 1.1440x over previous
//
#include <hip/hip_runtime.h>
#include <hip/hip_bf16.h>

typedef unsigned short ushort;
typedef unsigned int uint;
typedef __bf16 bf16x8 __attribute__((ext_vector_type(8)));
typedef float f32x4 __attribute__((ext_vector_type(4)));
typedef ushort ushort8 __attribute__((ext_vector_type(8)));

#define LOG2E 1.4426950408889634f
#define MFMA16(a,b,c) __builtin_amdgcn_mfma_f32_16x16x32_bf16((a),(b),(c),0,0,0)
#define GLL16(src, dst) __builtin_amdgcn_global_load_lds( \
    (const __attribute__((address_space(1))) void*)(src), \
    (__attribute__((address_space(3))) void*)(dst), 16, 0, 0)
#define GLL4(src, dst) __builtin_amdgcn_global_load_lds( \
    (const __attribute__((address_space(1))) void*)(src), \
    (__attribute__((address_space(3))) void*)(dst), 4, 0, 0)

static __device__ __forceinline__ uint packbf(float lo, float hi) {
  union { __bf16 h[2]; uint u; } x;
  x.h[0] = (__bf16)lo; x.h[1] = (__bf16)hi;
  return x.u;
}
static __device__ __forceinline__ int cellof(float x) {
  int c = (int)(x * 0.015625f);           // /64
  return c < 0 ? 0 : (c > 9 ? 9 : c);
}

// ---------------------------------------------------------------------------
// prep: [0,64) cast weights (16 blk/matrix x 16 el/thread) |
//       [64,8256) cast nodes | [8256,8384) hist | [8384,8448) meansum.
//       hist/meanN pre-zeroed by memsetAsync.
// ---------------------------------------------------------------------------
__global__ __launch_bounds__(256) void prep_kernel(
    const float* __restrict__ Wq, const float* __restrict__ Wk,
    const float* __restrict__ Wv, const float* __restrict__ Wm,
    __bf16* __restrict__ wsW,
    const float* __restrict__ n0, const float* __restrict__ n1,
    __bf16* __restrict__ a0, __bf16* __restrict__ a1,
    const float* __restrict__ kpred, const float* __restrict__ kact,
    int* __restrict__ hist, int* __restrict__ cellpt,
    float* __restrict__ meanN)
{
  const int bid = blockIdx.x, tid = threadIdx.x;
  if (bid < 64) {
    const int which = bid >> 4;
    const float* src = which == 0 ? Wq : which == 1 ? Wk : which == 2 ? Wv : Wm;
    const int i = (bid & 15) * 4096 + tid * 16;   // 16 blocks x 4096 el = 65536
    #pragma unroll
    for (int j2 = 0; j2 < 4; j2++) {
      f32x4 v = *(const f32x4*)(src + i + j2 * 4);
      union { __bf16 h[4]; uint u[2]; } x;
      #pragma unroll
      for (int j = 0; j < 4; j++) x.h[j] = (__bf16)v[j];
      *(uint*)(wsW + (size_t)which * 65536 + i + j2 * 4) = x.u[0];
      *(uint*)(wsW + (size_t)which * 65536 + i + j2 * 4 + 2) = x.u[1];
    }
  } else if (bid < 8256) {
    const int k = bid - 64;
    const float* s = k < 4096 ? n0 : n1;
    __bf16* o = k < 4096 ? a0 : a1;
    const int i = (k & 4095) * 1024 + tid * 4;
    f32x4 v = *(const f32x4*)(s + i);
    union { __bf16 h[4]; uint u[2]; } x;
    #pragma unroll
    for (int j = 0; j < 4; j++) x.h[j] = (__bf16)v[j];
    *(uint*)(o + i) = x.u[0];
    *(uint*)(o + i + 2) = x.u[1];
  } else if (bid < 8384) {
    const int p = (bid - 8256) * 256 + tid;       // 0..32767
    const int type = p >> 14, idx = p & 16383;
    const float2 c = ((const float2*)(type == 0 ? kpred : kact))[idx];
    const int cell = cellof(c.x) * 10 + cellof(c.y);
    const int b = idx >> 12;
    atomicAdd(&hist[(type * 4 + b) * 128 + cell], 1);
    cellpt[type * 16384 + idx] = cell;
  } else {
    const int mb = bid - 8384;
    const int b = mb >> 4, chunk = mb & 15;
    const float* base = n1 + ((size_t)b * 4096 + chunk * 256) * 256 + tid;
    float s = 0.f;
    for (int r = 0; r < 256; r++) s += base[(size_t)r * 256];
    atomicAdd(&meanN[b * 256 + tid], s);
  }
}

// ---------------------------------------------------------------------------
// scan (block 0) + vmean (blocks 1..4)
// ---------------------------------------------------------------------------
__global__ __launch_bounds__(256) void scan_vmean(
    const int* __restrict__ hist, int* __restrict__ strt, int* __restrict__ curs,
    const float* __restrict__ meanN, const float* __restrict__ Wv,
    const float* __restrict__ bv, float* __restrict__ Vmean)
{
  __shared__ int sh[1024];
  __shared__ float mn[256];
  const int t = threadIdx.x;
  if (blockIdx.x == 0) {
    for (int i = t; i < 1024; i += 256) sh[i] = hist[i];
    __syncthreads();
    if (t < 8) {
      int run = 0;
      for (int c = 0; c < 100; c++) {
        strt[t * 128 + c] = run;
        curs[t * 128 + c] = run;
        run += sh[t * 128 + c];
      }
      strt[t * 128 + 100] = run;   // sentinel (=4096)
    }
  } else {
    const int b = blockIdx.x - 1;
    mn[t] = meanN[b * 256 + t] * (1.0f / 4096.0f);
    __syncthreads();
    float s = bv[t];
    const float* w = Wv + (size_t)t * 256;
    for (int c = 0; c < 256; c++) s += mn[c] * w[c];
    Vmean[b * 256 + t] = s;
  }
}

// ---------------------------------------------------------------------------
// scatter: sorted index arrays, inverse perms, sorted coords (both types)
// ---------------------------------------------------------------------------
__global__ __launch_bounds__(256) void scatter_kernel(
    const float* __restrict__ kpred, const float* __restrict__ kact,
    const int* __restrict__ cellpt, int* __restrict__ curs,
    int* __restrict__ sq, int* __restrict__ invq, float* __restrict__ kpS,
    int* __restrict__ sk, int* __restrict__ invk, float* __restrict__ kaS)
{
  int p = blockIdx.x * 256 + threadIdx.x;
  int type = p >> 14, idx = p & 16383;
  int b = idx >> 12, n = idx & 4095;
  int cell = cellpt[type * 16384 + idx];
  int pos = atomicAdd(&curs[(type * 4 + b) * 128 + cell], 1);
  if (type == 0) {
    sq[b * 4096 + pos] = n;
    invq[b * 4096 + n] = pos;
    ((float2*)kpS)[b * 4096 + pos] = ((const float2*)kpred)[idx];
  } else {
    sk[b * 4096 + pos] = n;
    invk[b * 4096 + n] = pos;
    ((float2*)kaS)[b * 4096 + pos] = ((const float2*)kact)[idx];
  }
}

// ---------------------------------------------------------------------------
// Q/K/V projection GEMM, bf16 A. z=0: Q only. z=1: K and V fused (A read once).
// Outputs row-scattered into sorted order (coalesced 512B rows).
// ---------------------------------------------------------------------------
__global__ __launch_bounds__(256) void gemm_qkv(
    const ushort* __restrict__ A0, const ushort* __restrict__ A1,
    const ushort* __restrict__ W4,
    const float* __restrict__ bq, const float* __restrict__ bk,
    const float* __restrict__ bv,
    __bf16* __restrict__ outQ, __bf16* __restrict__ outK,
    __bf16* __restrict__ outVs,
    const int* __restrict__ invq, const int* __restrict__ invk)
{
  const int z = blockIdx.z;
  const ushort* A = z == 0 ? A0 : A1;
  const ushort* Wa = z == 0 ? W4 : W4 + 65536;       // Wq or Wk
  const ushort* Wb = W4 + 131072;                    // Wv (z=1 only)
  const int* inv = z == 0 ? invq : invk;

  const int wid = threadIdx.x >> 6;
  const int lane = threadIdx.x & 63;
  const int q = lane & 15, g = lane >> 4;
  const int nb = blockIdx.x * 64 + (wid >> 1) * 32;
  const int db = blockIdx.y * 128 + (wid & 1) * 64;

  f32x4 acc[2][4], accv[2][4];
  #pragma unroll
  for (int a = 0; a < 2; a++)
    #pragma unroll
    for (int b = 0; b < 4; b++) {
      acc[a][b] = f32x4{0.f,0.f,0.f,0.f};
      accv[a][b] = f32x4{0.f,0.f,0.f,0.f};
    }

  const ushort* Wa0 = Wa + (size_t)(db + q) * 256 + g * 8;
  const ushort* Wb0 = Wb + (size_t)(db + q) * 256 + g * 8;
  const ushort* Ar0 = A + (size_t)(nb + q) * 256 + g * 8;
  const ushort* Ar1 = A + (size_t)(nb + 16 + q) * 256 + g * 8;

  #pragma unroll
  for (int c0 = 0; c0 < 256; c0 += 32) {
    bf16x8 a0 = *(const bf16x8*)(Ar0 + c0);
    bf16x8 a1 = *(const bf16x8*)(Ar1 + c0);
    #pragma unroll
    for (int df = 0; df < 4; df++) {
      bf16x8 w = *(const bf16x8*)(Wa0 + df * 16 * 256 + c0);
      acc[0][df] = MFMA16(a0, w, acc[0][df]);
      acc[1][df] = MFMA16(a1, w, acc[1][df]);
    }
    if (z == 1) {
      #pragma unroll
      for (int df = 0; df < 4; df++) {
        bf16x8 w = *(const bf16x8*)(Wb0 + df * 16 * 256 + c0);
        accv[0][df] = MFMA16(a0, w, accv[0][df]);
        accv[1][df] = MFMA16(a1, w, accv[1][df]);
      }
    }
  }
  const float* biasA = z == 0 ? bq : bk;
  __bf16* oA = z == 0 ? outQ : outK;
  #pragma unroll
  for (int df = 0; df < 4; df++) {
    float ba = biasA[db + df * 16 + q];
    float bb = bv[db + df * 16 + q];
    #pragma unroll
    for (int nf = 0; nf < 2; nf++)
      #pragma unroll
      for (int r = 0; r < 4; r++) {
        int row = nb + nf * 16 + g * 4 + r;
        int d = db + df * 16 + q;
        int pos = inv[row];
        size_t orow = (size_t)(row & ~4095) + pos;
        oA[orow * 256 + d] = (__bf16)(acc[nf][df][r] + ba);
        if (z == 1)
          outVs[orow * 256 + d] = (__bf16)(accv[nf][df][r] + bb);
      }
  }
}

// ---------------------------------------------------------------------------
// transpose V_s [4][4096][256] -> VT [4][256][4096], LDS 64x64 tiles
// ---------------------------------------------------------------------------
__global__ __launch_bounds__(256) void transpose_v(
    const ushort* __restrict__ Vs, ushort* __restrict__ VT)
{
  __shared__ ushort tile[64][76];
  const int b = blockIdx.z, rt = blockIdx.x, dt = blockIdx.y;
  const int tid = threadIdx.x;
  const ushort* src = Vs + ((size_t)b * 4096 + rt * 64) * 256 + dt * 64;
  #pragma unroll
  for (int i = 0; i < 2; i++) {
    int c = tid + i * 256;
    int r = c >> 3, dc = (c & 7) * 8;
    ushort8 v = *(const ushort8*)(src + (size_t)r * 256 + dc);
    #pragma unroll
    for (int j = 0; j < 8; j++) tile[r][dc + j] = v[j];
  }
  __syncthreads();
  ushort* dst = VT + ((size_t)b * 256 + dt * 64) * 4096 + rt * 64;
  #pragma unroll
  for (int i = 0; i < 2; i++) {
    int c = tid + i * 256;
    int d = c >> 3, rc = (c & 7) * 8;
    ushort8 v;
    #pragma unroll
    for (int j = 0; j < 8; j++) v[j] = tile[rc + j][d];
    *(ushort8*)(dst + (size_t)d * 4096 + rc) = v;
  }
}

// ---------------------------------------------------------------------------
// Cooperative cell-block sparse flash attention.  Line-coalesced GLL staging:
// each GLL16 reads contiguous global (K: 2 full rows/inst; V: 16 full 64B
// lines/inst).  Slot permutation carried on the GLOBAL source side (rule #21):
//   K: LDS[r][u] holds global chunk u^(r&7)      (read: u0 = chunk ^ (q&7))
//   V: LDS[d][c] holds global chunk c^((d>>1)&3) (read: vs = g ^ ((q>>1)&3))
// Both read patterns uniform 8 slots/bank = conflict-free.
// ---------------------------------------------------------------------------
__global__ __launch_bounds__(256, 2) void attn_kernel(
    const ushort* __restrict__ Q,    // sorted Q_s [B*4096][256]
    const ushort* __restrict__ K,    // sorted K_s [B*4096][256]
    const ushort* __restrict__ VT,   // sorted VT_s [4][256][4096]
    const float* __restrict__ kpS,   // sorted pred coords
    const int* __restrict__ iter_idx,
    const int* __restrict__ sq,      // sorted->original query index
    const int* __restrict__ strt,    // [8][128], key segs at +4*128
    const float* __restrict__ kaS,   // sorted key coords
    const float* __restrict__ Vmean,
    __bf16* __restrict__ matched,
    float* __restrict__ out_flow, float* __restrict__ out_conf)
{
  __shared__ __align__(16) ushort Kl[2][8192];   // [buf][(r*32+u')*8]
  __shared__ __align__(16) ushort Vl[2][8192];   // [buf][(d*4+c')*8]
  __shared__ __align__(16) float2 Cl[2][32];
  __shared__ int tl_t[132], tl_ks[132], tl_ke[132];
  __shared__ int ntile_s;

  const int tid = threadIdx.x;
  const int wid = tid >> 6, lane = tid & 63;
  const int q = lane & 15, g = lane >> 4;
  // bijective XCD swizzle: each XCD gets 50 consecutive wgids (half a batch)
  const int orig = blockIdx.x;
  const int wgid = (orig & 7) * 50 + (orig >> 3);
  const int batch = wgid / 100;
  const int cell = wgid % 100;

  const int qstart = strt[batch * 128 + cell];
  const int nq = strt[batch * 128 + cell + 1] - qstart;
  if (nq == 0) return;

  const int cu = cell / 10, cv = cell % 10;
  const int c0 = cv > 0 ? cv - 1 : 0, c1 = cv < 9 ? cv + 1 : 9;
  const int* kst = strt + (4 + batch) * 128;

  if (tid == 0) {
    int n = 0;
    int lo = cu > 0 ? cu - 1 : 0, hi = cu < 9 ? cu + 1 : 9;
    for (int cc = lo; cc <= hi; cc++) {
      int ks = kst[cc * 10 + c0];
      int ke = kst[cc * 10 + c1 + 1];
      for (int t = ks & ~31; t < ke; t += 32) {
        tl_t[n] = t; tl_ks[n] = ks; tl_ke[n] = ke; n++;
      }
    }
    ntile_s = n;
  }
  __syncthreads();
  const int ntile = ntile_s;

  const int idx = *iter_idx;
  const float win = (idx == 0) ? 64.0f : fmaxf(4.0f, ldexpf(32.0f, 1 - idx));

  const ushort* Kbase = K + (size_t)batch * 4096 * 256;
  const ushort* VTb = VT + (size_t)batch * 1048576;
  const float* kasf = kaS + (size_t)batch * 8192;
  const float* Vm = Vmean + batch * 256;

  const int npass = (nq + 63) >> 6;

  // cooperative coalesced stage of tile `ti` into buffer `b`
  auto STAGE = [&](int ti, int b) {
    const int t = tl_t[ti];
    #pragma unroll
    for (int j = 0; j < 4; j++) {
      // K: lane n -> row r=n>>5, slot u=n&31; source chunk u^(r&7)
      int n = wid * 256 + j * 64 + lane;
      int r = n >> 5, u = n & 31;
      GLL16(Kbase + (size_t)(t + r) * 256 + ((u ^ (r & 7)) * 8),
            &Kl[b][(size_t)(wid * 256 + j * 64) * 8]);
    }
    #pragma unroll
    for (int j = 0; j < 4; j++) {
      // V: lane n -> d=n>>2, slot c=n&3; source chunk c^((d>>1)&3)
      int n = wid * 256 + j * 64 + lane;
      int d = n >> 2, c = n & 3;
      GLL16(VTb + (size_t)d * 4096 + t + ((c ^ ((d >> 1) & 3)) * 8),
            &Vl[b][(size_t)(wid * 256 + j * 64) * 8]);
    }
    if (wid == 0) GLL4(kasf + t * 2 + lane, &Cl[b][0]);
  };

  // per-pass / per-wave query state
  int cnt = 0, qi = 0;
  bool active = false;
  float pu = 0.f, pv = 0.f;
  bf16x8 qf[8];
  f32x4 O[16];
  float m_run = -1e9f, l_run = 0.f, u_run = 0.f, v_run = 0.f;

  auto PASS_INIT = [&](int pp) {
    int tbase = pp * 64 + wid * 16;
    active = tbase < nq;
    cnt = active ? min(16, nq - tbase) : 0;
    if (active) {
      int qq = q < cnt ? q : cnt - 1;
      int qsrow = batch * 4096 + qstart + tbase + qq;
      qi = sq[qsrow];
      const ushort* qptr = Q + (size_t)qsrow * 256 + g * 8;
      #pragma unroll
      for (int mf = 0; mf < 8; mf++) qf[mf] = *(const bf16x8*)(qptr + mf * 32);
      float2 kpv = ((const float2*)kpS)[qsrow];
      pu = kpv.x; pv = kpv.y;
    }
    #pragma unroll
    for (int i = 0; i < 16; i++) O[i] = f32x4{0.f,0.f,0.f,0.f};
    m_run = -1e9f; l_run = 0.f; u_run = 0.f; v_run = 0.f;
  };

  auto EPILOGUE = [&]() {
    if (!active) return;
    l_run += __shfl_xor(l_run, 16); l_run += __shfl_xor(l_run, 32);
    u_run += __shfl_xor(u_run, 16); u_run += __shfl_xor(u_run, 32);
    v_run += __shfl_xor(v_run, 16); v_run += __shfl_xor(v_run, 32);
    bool degen = (m_run <= -5e8f) || (l_run == 0.f);
    float rinv = degen ? 0.f : 1.0f / l_run;
    if (g == 0 && q < cnt) {
      float conf = degen ? 0.f : 1.0f;
      int row = batch * 4096 + qi;
      float fu = (u_run * rinv - pu) * conf, fv = (v_run * rinv - pv) * conf;
      ((float2*)out_flow)[row] = float2{fu, fv};
      out_conf[row] = conf;
    }
    #pragma unroll
    for (int r = 0; r < 4; r++) {
      int src = 4 * g + r;
      int qi_r = __shfl(qi, src);
      float il_r = __shfl(rinv, src);
      bool dg_r = (il_r == 0.f);
      if (src < cnt) {
        __bf16* mrow = matched + ((size_t)batch * 4096 + qi_r) * 256;
        #pragma unroll
        for (int df = 0; df < 16; df++) {
          float val = dg_r ? Vm[df * 16 + q] : O[df][r] * il_r;
          mrow[df * 16 + q] = (__bf16)val;
        }
      }
    }
  };

  if (ntile == 0) {
    for (int pp = 0; pp < npass; pp++) { PASS_INIT(pp); EPILOGUE(); }
    return;
  }

  const int total = npass * ntile;
  STAGE(0, 0);
  PASS_INIT(0);

  int i = 0, pp = 0;
  for (int it = 0; it < total; ++it) {
    __syncthreads();   // stage(it) done; everyone's compute(it-1) done
    if (it + 1 < total) {
      int ni = (i + 1 == ntile) ? 0 : i + 1;
      STAGE(ni, (it + 1) & 1);
    }
    const int b = it & 1;

    if (active) {
      const int t = tl_t[i], ks = tl_ks[i], ke = tl_ke[i];

      // ---- QK^T from staged K (row-major, source-swizzled slots) ----
      f32x4 s0a = {0.f,0.f,0.f,0.f}, s0b = {0.f,0.f,0.f,0.f};
      f32x4 s1a = {0.f,0.f,0.f,0.f}, s1b = {0.f,0.f,0.f,0.f};
      #pragma unroll
      for (int mf = 0; mf < 8; mf += 2) {
        const int u0 = (mf * 4 + g) ^ (q & 7);
        const int u1 = ((mf + 1) * 4 + g) ^ (q & 7);
        bf16x8 ka0 = *(const bf16x8*)&Kl[b][(size_t)(q * 32 + u0) * 8];
        bf16x8 kb0 = *(const bf16x8*)&Kl[b][(size_t)(q * 32 + u1) * 8];
        bf16x8 ka1 = *(const bf16x8*)&Kl[b][(size_t)((q + 16) * 32 + u0) * 8];
        bf16x8 kb1 = *(const bf16x8*)&Kl[b][(size_t)((q + 16) * 32 + u1) * 8];
        s0a = MFMA16(ka0, qf[mf],     s0a);
        s0b = MFMA16(kb0, qf[mf + 1], s0b);
        s1a = MFMA16(ka1, qf[mf],     s1a);
        s1b = MFMA16(kb1, qf[mf + 1], s1b);
      }

      float aus[8], avs[8], sv[8];
      #pragma unroll
      for (int r = 0; r < 4; r++) {
        int jr = t + 4 * g + r;
        float2 cc0 = Cl[b][4 * g + r];
        aus[r] = cc0.x; avs[r] = cc0.y;
        bool val = (jr >= ks && jr < ke);
        float du = fabsf(pu - cc0.x), dv = fabsf(pv - cc0.y);
        float sr = s0a[r] + s0b[r];
        sv[r] = (val && fmaxf(du, dv) < win) ? sr * 0.0625f : -1e9f;

        int jr1 = jr + 16;
        float2 cc1 = Cl[b][16 + 4 * g + r];
        aus[4 + r] = cc1.x; avs[4 + r] = cc1.y;
        val = (jr1 >= ks && jr1 < ke);
        du = fabsf(pu - cc1.x); dv = fabsf(pv - cc1.y);
        sr = s1a[r] + s1b[r];
        sv[4 + r] = (val && fmaxf(du, dv) < win) ? sr * 0.0625f : -1e9f;
      }

      float mt = fmaxf(fmaxf(fmaxf(sv[0], sv[1]), fmaxf(sv[2], sv[3])),
                       fmaxf(fmaxf(sv[4], sv[5]), fmaxf(sv[6], sv[7])));
      mt = fmaxf(mt, __shfl_xor(mt, 16));
      mt = fmaxf(mt, __shfl_xor(mt, 32));
      if (__any(mt > m_run + 8.0f)) {       // defer-rescale (T13)
        float m_new = fmaxf(m_run, mt);
        float scale = exp2f((m_run - m_new) * LOG2E);
        l_run *= scale; u_run *= scale; v_run *= scale;
        float s_r[4];
        #pragma unroll
        for (int r = 0; r < 4; r++) s_r[r] = __shfl(scale, 4 * g + r);
        #pragma unroll
        for (int df = 0; df < 16; df++)
          #pragma unroll
          for (int r = 0; r < 4; r++) O[df][r] *= s_r[r];
        m_run = m_new;
      }

      float p[8];
      #pragma unroll
      for (int ii = 0; ii < 8; ii++) p[ii] = exp2f((sv[ii] - m_run) * LOG2E);
      #pragma unroll
      for (int ii = 0; ii < 8; ii++) {
        l_run += p[ii];
        u_run += p[ii] * aus[ii];
        v_run += p[ii] * avs[ii];
      }

      // pack P^T(C layout) -> A-operand layout via lane exchange
      uint d0 = packbf(p[0], p[1]), d1 = packbf(p[2], p[3]);
      uint d2 = packbf(p[4], p[5]), d3 = packbf(p[6], p[7]);
      int srcA = q + ((g & 1) << 5);
      int srcB = srcA + 16;
      uint x0 = (uint)__shfl((int)d0, srcA), x1 = (uint)__shfl((int)d1, srcA);
      uint x2 = (uint)__shfl((int)d0, srcB), x3 = (uint)__shfl((int)d1, srcB);
      uint y0 = (uint)__shfl((int)d2, srcA), y1 = (uint)__shfl((int)d3, srcA);
      uint y2 = (uint)__shfl((int)d2, srcB), y3 = (uint)__shfl((int)d3, srcB);
      union { uint i4[4]; bf16x8 v; } af;
      bool lo = (g < 2);
      af.i4[0] = lo ? x0 : y0; af.i4[1] = lo ? x1 : y1;
      af.i4[2] = lo ? x2 : y2; af.i4[3] = lo ? x3 : y3;

      // PV from staged V (d-row-major, source-swizzled slots)
      const int vs = g ^ ((q >> 1) & 3);
      #pragma unroll
      for (int df = 0; df < 16; df++) {
        bf16x8 vfd = *(const bf16x8*)&Vl[b][(size_t)((df * 16 + q) * 4 + vs) * 8];
        O[df] = MFMA16(af.v, vfd, O[df]);
      }
    }

    if (i == ntile - 1) {            // end of pass
      EPILOGUE();
      pp++;
      if (pp < npass) PASS_INIT(pp);
      i = 0;
    } else {
      i++;
    }
  }
}

// ---------------------------------------------------------------------------
// merged GEMM (blocks 0..511) + geo MLP (blocks 512..575)
// ---------------------------------------------------------------------------
__global__ __launch_bounds__(256) void merged_geo(
    const ushort* __restrict__ A, const ushort* __restrict__ W,
    const float* __restrict__ bias, float* __restrict__ out,
    const float* __restrict__ flow, const float* __restrict__ conf_in,
    const float* __restrict__ Wg1, const float* __restrict__ bg1,
    const float* __restrict__ Wg2, const float* __restrict__ bg2,
    float* __restrict__ out_geo)
{
  __shared__ float w1[32][3], b1[32], b2[32];
  __shared__ __align__(16) float w2[32][32];
  if (blockIdx.x < 512) {
    const int wid = threadIdx.x >> 6;
    const int lane = threadIdx.x & 63;
    const int q = lane & 15, g = lane >> 4;
    const int nb = (blockIdx.x >> 1) * 64 + (wid >> 1) * 32;
    const int db = (blockIdx.x & 1) * 128 + (wid & 1) * 64;

    f32x4 acc[2][4];
    #pragma unroll
    for (int a = 0; a < 2; a++)
      #pragma unroll
      for (int b = 0; b < 4; b++) acc[a][b] = f32x4{0.f,0.f,0.f,0.f};

    const ushort* W0 = W + (size_t)(db + q) * 256 + g * 8;
    const ushort* Ar0 = A + (size_t)(nb + q) * 256 + g * 8;
    const ushort* Ar1 = A + (size_t)(nb + 16 + q) * 256 + g * 8;

    #pragma unroll
    for (int c0 = 0; c0 < 256; c0 += 32) {
      bf16x8 a0 = *(const bf16x8*)(Ar0 + c0);
      bf16x8 a1 = *(const bf16x8*)(Ar1 + c0);
      #pragma unroll
      for (int df = 0; df < 4; df++) {
        bf16x8 w = *(const bf16x8*)(W0 + df * 16 * 256 + c0);
        acc[0][df] = MFMA16(a0, w, acc[0][df]);
        acc[1][df] = MFMA16(a1, w, acc[1][df]);
      }
    }
    #pragma unroll
    for (int df = 0; df < 4; df++) {
      float bval = bias[db + df * 16 + q];
      #pragma unroll
      for (int nf = 0; nf < 2; nf++)
        #pragma unroll
        for (int r = 0; r < 4; r++) {
          int row = nb + nf * 16 + g * 4 + r;
          out[(size_t)row * 256 + db + df * 16 + q] = acc[nf][df][r] + bval;
        }
    }
  } else {
    const int tid = threadIdx.x;
    for (int i = tid; i < 96; i += 256) w1[i / 3][i % 3] = Wg1[i];
    if (tid < 32) { b1[tid] = bg1[tid]; b2[tid] = bg2[tid]; }
    for (int i = tid; i < 1024; i += 256) w2[i / 32][i % 32] = Wg2[i];
    __syncthreads();

    int row = (blockIdx.x - 512) * 256 + tid;
    float2 f = ((const float2*)flow)[row];
    float c = conf_in[row];
    float h[32];
    #pragma unroll
    for (int j = 0; j < 32; j++) {
      float x = w1[j][0] * f.x + w1[j][1] * f.y + w1[j][2] * c + b1[j];
      h[j] = x / (1.f + __expf(-x));
    }
    #pragma unroll
    for (int o = 0; o < 32; o += 2) {
      float s0 = b2[o], s1 = b2[o + 1];
      #pragma unroll
      for (int j = 0; j < 32; j += 4) {
        f32x4 wa = *(const f32x4*)&w2[o][j];
        f32x4 wb = *(const f32x4*)&w2[o + 1][j];
        s0 += wa[0]*h[j] + wa[1]*h[j+1] + wa[2]*h[j+2] + wa[3]*h[j+3];
        s1 += wb[0]*h[j] + wb[1]*h[j+1] + wb[2]*h[j+2] + wb[3]*h[j+3];
      }
      ((float2*)out_geo)[((size_t)row * 32 + o) >> 1] = float2{s0, s1};
    }
  }
}

// ---------------------------------------------------------------------------
extern "C" void kernel_launch(void* const* d_in, const int* in_sizes, int n_in,
                              void* d_out, int out_size, void* d_ws, size_t ws_size,
                              hipStream_t stream) {
  const float* nodes_t  = (const float*)d_in[0];
  const float* nodes_t1 = (const float*)d_in[1];
  const float* kpred    = (const float*)d_in[2];
  const float* kact     = (const float*)d_in[3];
  const float* Wq = (const float*)d_in[4];  const float* bq = (const float*)d_in[5];
  const float* Wk = (const float*)d_in[6];  const float* bk = (const float*)d_in[7];
  const float* Wv = (const float*)d_in[8];  const float* bv = (const float*)d_in[9];
  const float* Wm = (const float*)d_in[10]; const float* bm = (const float*)d_in[11];
  const float* Wg1= (const float*)d_in[12]; const float* bg1= (const float*)d_in[13];
  const float* Wg2= (const float*)d_in[14]; const float* bg2= (const float*)d_in[15];
  const int* iter = (const int*)d_in[16];

  float* out_merged = (float*)d_out;                 // 4*4096*256
  float* out_geo  = out_merged + 4 * 4096 * 256;     // 4*4096*32
  float* out_flow = out_geo + 4 * 4096 * 32;         // 4*4096*2
  float* out_conf = out_flow + 4 * 4096 * 2;         // 4*4096

  ushort* wsQ   = (ushort*)d_ws;        // bf16 4194304 el each (sorted)
  ushort* wsK   = wsQ + 4194304;        // sorted K_s
  ushort* wsVT  = wsK + 4194304;        // VT_s [4][256][4096] sorted keys
  ushort* wsM   = wsVT + 4194304;       // matched; doubles as V_s staging
  ushort* wsW   = wsM + 4194304;        // bf16 4*65536
  float*  kaS   = (float*)(wsW + 262144);   // 32768 f32
  float*  kpS   = kaS + 32768;              // 32768
  float*  Vmean = kpS + 32768;              // 1024
  int*    hist  = (int*)(Vmean + 1024);     // 1024   <- memset region start
  float*  meanN = (float*)(hist + 1024);    // 1024   <- memset region end
  int*    strt  = (int*)(meanN + 1024);     // 1024
  int*    curs  = strt + 1024;              // 1024
  int*    cellpt= curs + 1024;              // 32768
  int*    sq    = cellpt + 32768;           // 16384
  int*    sk    = sq + 16384;               // 16384
  int*    invk  = sk + 16384;               // 16384
  int*    invq  = invk + 16384;             // 16384
  ushort* wsA0  = (ushort*)(invq + 16384);  // bf16 nodes_t   4194304
  ushort* wsA1  = wsA0 + 4194304;           // bf16 nodes_t1  4194304

  hipMemsetAsync(hist, 0, 8192, stream);    // hist + meanN

  prep_kernel<<<8448, 256, 0, stream>>>(Wq, Wk, Wv, Wm, (__bf16*)wsW,
                                        nodes_t, nodes_t1,
                                        (__bf16*)wsA0, (__bf16*)wsA1,
                                        kpred, kact, hist, cellpt, meanN);
  scan_vmean<<<5, 256, 0, stream>>>(hist, strt, curs, meanN, Wv, bv, Vmean);
  scatter_kernel<<<128, 256, 0, stream>>>(kpred, kact, cellpt, curs,
                                          sq, invq, kpS, sk, invk, kaS);
  dim3 qg(256, 2, 2);
  gemm_qkv<<<qg, 256, 0, stream>>>(wsA0, wsA1, wsW, bq, bk, bv,
                                   (__bf16*)wsQ, (__bf16*)wsK, (__bf16*)wsM,
                                   invq, invk);
  dim3 tg(64, 4, 4);
  transpose_v<<<tg, 256, 0, stream>>>(wsM, wsVT);
  attn_kernel<<<400, 256, 0, stream>>>(wsQ, wsK, wsVT, kpS, iter,
                                       sq, strt, kaS, Vmean,
                                       (__bf16*)wsM, out_flow, out_conf);
  merged_geo<<<576, 256, 0, stream>>>(wsM, wsW + 196608, bm, out_merged,
                                      out_flow, out_conf,
                                      Wg1, bg1, Wg2, bg2, out_geo);
}